// Round 1
// 14705.869 us; speedup vs baseline: 1.1256x; 1.1256x over previous
//
#include <hip/hip_runtime.h>
#include <math.h>

// Decoder: B=1024, Z=256, TDIM=512, CF=1024, A=64, R=128, T=64
// R8: prefetch-pipelined K-loop (T3/T4 minimum 2-phase): BK 64->32, double-buffered
//     LDS (same footprint: step3 2x32KB, step1 2x24KB), STAGE(next) issued BEFORE
//     compute(cur), counted s_waitcnt vmcnt(8)/(6) + raw s_barrier (no __syncthreads
//     vmcnt(0) drain). Accumulation order per K-chunk preserved -> bit-identical
//     numerics vs R7. Epilogues, heads, setup unchanged.

__device__ __forceinline__ float sigf(float x) { return 1.0f / (1.0f + expf(-x)); }

typedef __attribute__((ext_vector_type(8))) _Float16 f16x8;
typedef __attribute__((ext_vector_type(4))) float f32x4;

__device__ __forceinline__ void split_f16(float x, unsigned short& hi, unsigned short& lo) {
    _Float16 h = (_Float16)x;                   // RNE f32->f16
    float r = (x - (float)h) * 2048.0f;         // exact
    _Float16 l = (_Float16)r;
    hi = __builtin_bit_cast(unsigned short, h);
    lo = __builtin_bit_cast(unsigned short, l);
}

#define GLDS(gp, lp) __builtin_amdgcn_global_load_lds( \
    (const __attribute__((address_space(1))) void*)(gp), \
    (__attribute__((address_space(3))) void*)(lp), 16, 0, 0)

// ---------------- step1: a-cell GEMM+LSTM | u GEMM | res head ----------------
// a: 128x64 tiles (64 N = 4 gates x 16 j), 4 waves (wm=wave, 32 rows each), ni=gate.
// u: 128x64 tiles over N=512.
// L<512: a (XCD-swizzled); 512..575: u; 576..831: res head for step t-1.
__global__ __launch_bounds__(256) void step1(
    const unsigned short* __restrict__ Ah, const unsigned short* __restrict__ Al,
    const unsigned short* __restrict__ WA0, const unsigned short* __restrict__ WA1,
    const float* __restrict__ base_a, const float* __restrict__ Ea, const int* __restrict__ aidx,
    float* __restrict__ ca, unsigned short* __restrict__ oAh, unsigned short* __restrict__ oAl,
    float* __restrict__ haf,
    const unsigned short* __restrict__ Th, const unsigned short* __restrict__ Tl,
    const unsigned short* __restrict__ W10, const unsigned short* __restrict__ W11,
    const float* __restrict__ b1, float* __restrict__ u,
    const float* __restrict__ hrf, const float* __restrict__ resT4, const float* __restrict__ resb,
    float* __restrict__ out_res, int* __restrict__ ridx, int t, int Loff)
{
    int L = blockIdx.x + Loff;
    if (L >= 576) {
        // ---- res head for step t-1 ----
        if (t == 0) return;
        int lane = threadIdx.x & 63, w = threadIdx.x >> 6;
        int b = (L - 576) * 4 + w;
        float acc0 = resb[lane], acc1 = resb[lane + 64];
        const float4* arow = (const float4*)(hrf + (size_t)b * 1024);
#pragma unroll 4
        for (int k4 = 0; k4 < 256; k4++) {
            float4 a4 = arow[k4];
            float4 w40 = *(const float4*)(resT4 + ((size_t)k4 * 128 + lane) * 4);
            float4 w41 = *(const float4*)(resT4 + ((size_t)k4 * 128 + lane + 64) * 4);
            acc0 += a4.x * w40.x + a4.y * w40.y + a4.z * w40.z + a4.w * w40.w;
            acc1 += a4.x * w41.x + a4.y * w41.y + a4.z * w41.z + a4.w * w41.w;
        }
        float v = acc0; int idx = lane;
        if (acc1 > v) { v = acc1; idx = lane + 64; }
#pragma unroll
        for (int off = 32; off; off >>= 1) {
            float ov = __shfl_xor(v, off);
            int   oi = __shfl_xor(idx, off);
            if (ov > v || (ov == v && oi < idx)) { v = ov; idx = oi; }
        }
        float e0 = expf(acc0 - v), e1 = expf(acc1 - v);
        float s = e0 + e1;
#pragma unroll
        for (int off = 32; off; off >>= 1) s += __shfl_xor(s, off);
        float* dst = out_res + ((size_t)b * 64 + (t - 1)) * 128;
        dst[lane] = e0 / s; dst[lane + 64] = e1 / s;
        if (lane == 0) ridx[b] = idx;
        return;
    }

    // ---- GEMM part (a or u) ----
    // 48KB LDS: 2 bufs x 12288 ushorts {Ah[0,4096) Al[4096,8192) Bh[8192,10240) Bl[10240,12288)}
    __shared__ unsigned short lds[24576];
    const unsigned short *pAh, *pAl, *pWh, *pWl;
    int x, jy; bool isA;
    if (L < 512) {
        isA = true;
        int xcd = L & 7, idx = L >> 3;
        jy = xcd * 8 + (idx >> 3);       // j-tile 0..63 (j0 = jy*16)
        x = idx & 7;
        pAh = Ah; pAl = Al; pWh = WA0; pWl = WA1;
    } else {
        isA = false;
        int t2 = L - 512;
        x = t2 & 7; jy = t2 >> 3;        // u: n0 = jy*64
        pAh = Th; pAl = Tl; pWh = W10; pWl = W11;
    }
    const int tid = threadIdx.x, wave = tid >> 6, lane = tid & 63;
    const int lrow = lane & 15, lq = lane >> 4;
    const int m0 = x * 128;

    f32x4 acch[2][4], accl[2][4];
#pragma unroll
    for (int i = 0; i < 2; i++)
#pragma unroll
        for (int j = 0; j < 4; j++) {
            acch[i][j] = (f32x4){0.f, 0.f, 0.f, 0.f};
            accl[i][j] = (f32x4){0.f, 0.f, 0.f, 0.f};
        }

    const int nrow = isA ? (wave * 1024 + jy * 16 + lrow) : (jy * 64 + wave * 16 + lrow);

    // stage one BK=32 chunk into buffer p: 6 GLDS per wave (4 A-blocks + 2 B)
    auto STAGE = [&](int it, int p) {
        int k = it * 32 + lq * 8;
        unsigned short* bp = &lds[p * 12288];
#pragma unroll
        for (int ss = 0; ss < 2; ss++) {
            int s = wave * 2 + ss;
            int mrow = m0 + s * 16 + lrow;
            GLDS(pAh + (size_t)mrow * 1024 + k, bp + s * 512);
            GLDS(pAl + (size_t)mrow * 1024 + k, bp + 4096 + s * 512);
        }
        GLDS(pWh + (size_t)nrow * 1024 + k, bp + 8192 + wave * 512);
        GLDS(pWl + (size_t)nrow * 1024 + k, bp + 10240 + wave * 512);
    };
    // consume buffer p: 12 ds_read_b128 + 24 MFMA
    auto COMPUTE = [&](int p) {
        unsigned short* bp = &lds[p * 12288];
        f16x8 ah[2], al[2], bh[4], bl[4];
#pragma unroll
        for (int mi = 0; mi < 2; mi++) {
            ah[mi] = *(const f16x8*)(bp + (wave * 2 + mi) * 512 + lane * 8);
            al[mi] = *(const f16x8*)(bp + 4096 + (wave * 2 + mi) * 512 + lane * 8);
        }
#pragma unroll
        for (int ni = 0; ni < 4; ni++) {
            bh[ni] = *(const f16x8*)(bp + 8192 + ni * 512 + lane * 8);
            bl[ni] = *(const f16x8*)(bp + 10240 + ni * 512 + lane * 8);
        }
#pragma unroll
        for (int mi = 0; mi < 2; mi++)
#pragma unroll
            for (int ni = 0; ni < 4; ni++) {
                acch[mi][ni] = __builtin_amdgcn_mfma_f32_16x16x32_f16(ah[mi], bh[ni], acch[mi][ni], 0, 0, 0);
                accl[mi][ni] = __builtin_amdgcn_mfma_f32_16x16x32_f16(al[mi], bh[ni], accl[mi][ni], 0, 0, 0);
                accl[mi][ni] = __builtin_amdgcn_mfma_f32_16x16x32_f16(ah[mi], bl[ni], accl[mi][ni], 0, 0, 0);
            }
    };

    STAGE(0, 0);
    for (int it = 0; it < 31; ++it) {
        int cur = it & 1;
        STAGE(it + 1, cur ^ 1);                          // 6 GLDS in flight across compute
        asm volatile("s_waitcnt vmcnt(6)" ::: "memory"); // cur buffer's 6 complete (in-order)
        __builtin_amdgcn_s_barrier();
        __builtin_amdgcn_sched_barrier(0);
        COMPUTE(cur);
        __builtin_amdgcn_sched_barrier(0);
        __builtin_amdgcn_s_barrier();                    // reads of cur done before overwrite
    }
    asm volatile("s_waitcnt vmcnt(0)" ::: "memory");
    __builtin_amdgcn_s_barrier();
    __builtin_amdgcn_sched_barrier(0);
    COMPUTE(1);

    const float s_lo = 1.0f / 2048.0f;
    if (isA) {
        // fused LSTM-a epilogue: ni == gate, thread-local
        int j = jy * 16 + lrow;
#pragma unroll
        for (int mi = 0; mi < 2; mi++)
#pragma unroll
            for (int r = 0; r < 4; r++) {
                int row = m0 + wave * 32 + mi * 16 + lq * 4 + r;
                size_t rb = (size_t)row * 4096 + j;
                const float* e1 = Ea + (size_t)aidx[row] * 4096 + j;
                float gi = acch[mi][0][r] + accl[mi][0][r] * s_lo + base_a[rb]        + e1[0];
                float gf = acch[mi][1][r] + accl[mi][1][r] * s_lo + base_a[rb + 1024] + e1[1024];
                float gg = acch[mi][2][r] + accl[mi][2][r] * s_lo + base_a[rb + 2048] + e1[2048];
                float go = acch[mi][3][r] + accl[mi][3][r] * s_lo + base_a[rb + 3072] + e1[3072];
                size_t ci = (size_t)row * 1024 + j;
                float cn = sigf(gf) * ca[ci] + sigf(gi) * tanhf(gg);
                ca[ci] = cn;
                float hn = sigf(go) * tanhf(cn);
                haf[ci] = hn;
                split_f16(hn, oAh[ci], oAl[ci]);
            }
    } else {
        // u = relu(ht @ W1^T + b1)
#pragma unroll
        for (int mi = 0; mi < 2; mi++)
#pragma unroll
            for (int ni = 0; ni < 4; ni++) {
                int col = jy * 64 + ni * 16 + lrow;
                float bv = b1[col];
#pragma unroll
                for (int r = 0; r < 4; r++) {
                    int row = m0 + wave * 32 + mi * 16 + lq * 4 + r;
                    float v = acch[mi][ni][r] + accl[mi][ni][r] * s_lo + bv;
                    u[(size_t)row * 512 + col] = fmaxf(v, 0.0f);
                }
            }
    }
}

// ---------------- step3: r & t cell GEMM + fused LSTM epilogue ----------------
// 128x128 tiles (128 N = 4 gates x 32 j), waves 2x2 (wm rows, wn = j-half), ni=gate.
__global__ __launch_bounds__(256) void step3(
    const unsigned short* __restrict__ Rh, const unsigned short* __restrict__ Rl,
    const unsigned short* __restrict__ WR0, const unsigned short* __restrict__ WR1,
    const float* __restrict__ base_r, const float* __restrict__ Er_a, const float* __restrict__ Er_r,
    const int* __restrict__ aidx, const int* __restrict__ ridx, const float* __restrict__ tsv,
    float* __restrict__ cr, unsigned short* __restrict__ oRh, unsigned short* __restrict__ oRl,
    float* __restrict__ hrf,
    const unsigned short* __restrict__ Th, const unsigned short* __restrict__ Tl,
    const unsigned short* __restrict__ WT0, const unsigned short* __restrict__ WT1,
    const float* __restrict__ base_t, const float* __restrict__ Et_a, const float* __restrict__ wtts,
    float* __restrict__ ct, unsigned short* __restrict__ oTh, unsigned short* __restrict__ oTl)
{
    // 64KB LDS: 2 bufs x 16384 ushorts {Ah[0,4096) Al[4096,8192) Bh[8192,12288) Bl[12288,16384)}
    __shared__ unsigned short lds[32768];
    int L = blockIdx.x;
    int xcd = L & 7, idx = L >> 3;
    int g = xcd * 8 + (idx >> 3);            // 64 (z,y) groups
    int x = idx & 7;
    int z = g >> 5, y = g & 31;
    const unsigned short* pAh = z ? Th : Rh;
    const unsigned short* pAl = z ? Tl : Rl;
    const unsigned short* pWh = z ? WT0 : WR0;
    const unsigned short* pWl = z ? WT1 : WR1;

    const int tid = threadIdx.x, wave = tid >> 6, lane = tid & 63;
    const int wm = wave >> 1, wn = wave & 1;
    const int lrow = lane & 15, lq = lane >> 4;
    const int m0 = x * 128, j0 = y * 32;

    f32x4 acch[4][4], accl[4][4];
#pragma unroll
    for (int i = 0; i < 4; i++)
#pragma unroll
        for (int j = 0; j < 4; j++) {
            acch[i][j] = (f32x4){0.f, 0.f, 0.f, 0.f};
            accl[i][j] = (f32x4){0.f, 0.f, 0.f, 0.f};
        }

    // stage one BK=32 chunk into buffer p: 8 GLDS per wave
    auto STAGE = [&](int it, int p) {
        int k = it * 32 + lq * 8;
        unsigned short* bp = &lds[p * 16384];
#pragma unroll
        for (int ss = 0; ss < 2; ss++) {
            int s = wave * 2 + ss;
            int mrow = m0 + s * 16 + lrow;
            int nrow = (s >> 1) * 1024 + j0 + (s & 1) * 16 + lrow;   // gate = s>>1
            GLDS(pAh + (size_t)mrow * 1024 + k, bp + s * 512);
            GLDS(pAl + (size_t)mrow * 1024 + k, bp + 4096 + s * 512);
            GLDS(pWh + (size_t)nrow * 1024 + k, bp + 8192 + s * 512);
            GLDS(pWl + (size_t)nrow * 1024 + k, bp + 12288 + s * 512);
        }
    };
    // consume buffer p: 16 ds_read_b128 + 48 MFMA
    auto COMPUTE = [&](int p) {
        unsigned short* bp = &lds[p * 16384];
        f16x8 ah[4], al[4], bh[4], bl[4];
#pragma unroll
        for (int mi = 0; mi < 4; mi++) {
            ah[mi] = *(const f16x8*)(bp + (wm * 4 + mi) * 512 + lane * 8);
            al[mi] = *(const f16x8*)(bp + 4096 + (wm * 4 + mi) * 512 + lane * 8);
        }
#pragma unroll
        for (int ni = 0; ni < 4; ni++) {
            bh[ni] = *(const f16x8*)(bp + 8192 + (ni * 2 + wn) * 512 + lane * 8);
            bl[ni] = *(const f16x8*)(bp + 12288 + (ni * 2 + wn) * 512 + lane * 8);
        }
#pragma unroll
        for (int mi = 0; mi < 4; mi++)
#pragma unroll
            for (int ni = 0; ni < 4; ni++) {
                acch[mi][ni] = __builtin_amdgcn_mfma_f32_16x16x32_f16(ah[mi], bh[ni], acch[mi][ni], 0, 0, 0);
                accl[mi][ni] = __builtin_amdgcn_mfma_f32_16x16x32_f16(al[mi], bh[ni], accl[mi][ni], 0, 0, 0);
                accl[mi][ni] = __builtin_amdgcn_mfma_f32_16x16x32_f16(ah[mi], bl[ni], accl[mi][ni], 0, 0, 0);
            }
    };

    STAGE(0, 0);
    for (int it = 0; it < 31; ++it) {
        int cur = it & 1;
        STAGE(it + 1, cur ^ 1);                          // 8 GLDS in flight across compute
        asm volatile("s_waitcnt vmcnt(8)" ::: "memory"); // cur buffer's 8 complete (in-order)
        __builtin_amdgcn_s_barrier();
        __builtin_amdgcn_sched_barrier(0);
        COMPUTE(cur);
        __builtin_amdgcn_sched_barrier(0);
        __builtin_amdgcn_s_barrier();                    // reads of cur done before overwrite
    }
    asm volatile("s_waitcnt vmcnt(0)" ::: "memory");
    __builtin_amdgcn_s_barrier();
    __builtin_amdgcn_sched_barrier(0);
    COMPUTE(1);

    const float s_lo = 1.0f / 2048.0f;
    const int j = j0 + wn * 16 + lrow;
    if (z == 0) {
        // cell r
#pragma unroll
        for (int mi = 0; mi < 4; mi++)
#pragma unroll
            for (int r = 0; r < 4; r++) {
                int row = m0 + wm * 64 + mi * 16 + lq * 4 + r;
                size_t rb = (size_t)row * 4096 + j;
                const float* e1 = Er_a + (size_t)aidx[row] * 4096 + j;
                const float* e2 = Er_r + (size_t)ridx[row] * 4096 + j;
                float gi = acch[mi][0][r] + accl[mi][0][r] * s_lo + base_r[rb]        + e1[0]    + e2[0];
                float gf = acch[mi][1][r] + accl[mi][1][r] * s_lo + base_r[rb + 1024] + e1[1024] + e2[1024];
                float gg = acch[mi][2][r] + accl[mi][2][r] * s_lo + base_r[rb + 2048] + e1[2048] + e2[2048];
                float go = acch[mi][3][r] + accl[mi][3][r] * s_lo + base_r[rb + 3072] + e1[3072] + e2[3072];
                size_t ci = (size_t)row * 1024 + j;
                float cn = sigf(gf) * cr[ci] + sigf(gi) * tanhf(gg);
                cr[ci] = cn;
                float hn = sigf(go) * tanhf(cn);
                hrf[ci] = hn;
                split_f16(hn, oRh[ci], oRl[ci]);
            }
    } else {
        // cell t
#pragma unroll
        for (int mi = 0; mi < 4; mi++)
#pragma unroll
            for (int r = 0; r < 4; r++) {
                int row = m0 + wm * 64 + mi * 16 + lq * 4 + r;
                size_t rb = (size_t)row * 4096 + j;
                const float* e1 = Et_a + (size_t)aidx[row] * 4096 + j;
                float tv = tsv[row];
                float gi = acch[mi][0][r] + accl[mi][0][r] * s_lo + base_t[rb]        + e1[0];
                float gf = acch[mi][1][r] + accl[mi][1][r] * s_lo + base_t[rb + 1024] + e1[1024];
                float gg = acch[mi][2][r] + accl[mi][2][r] * s_lo + base_t[rb + 2048] + e1[2048];
                float go = acch[mi][3][r] + accl[mi][3][r] * s_lo + base_t[rb + 3072] + e1[3072];
                gi = fmaf(tv, wtts[j], gi);        gf = fmaf(tv, wtts[j + 1024], gf);
                gg = fmaf(tv, wtts[j + 2048], gg); go = fmaf(tv, wtts[j + 3072], go);
                size_t ci = (size_t)row * 1024 + j;
                float cn = sigf(gf) * ct[ci] + sigf(gi) * tanhf(gg);
                ct[ci] = cn;
                float hn = sigf(go) * tanhf(cn);
                split_f16(hn, oTh[ci], oTl[ci]);
            }
    }
}

// ---------------- heads: act softmax/argmax (blocks 0..255) + ts_final (256..511) ----------------
__global__ __launch_bounds__(256) void heads(
    const float* __restrict__ haf, const float* __restrict__ actT4, const float* __restrict__ actb,
    float* __restrict__ out_acts, int* __restrict__ aidx, int tact,
    const float* __restrict__ u, const float* __restrict__ w2, const float* __restrict__ b2,
    float* __restrict__ out_ts, float* __restrict__ tsv, int tts)
{
    int blk = blockIdx.x;
    int lane = threadIdx.x & 63, w = threadIdx.x >> 6;
    if (blk < 256) {
        if (tact < 0) return;
        int b = blk * 4 + w;
        float acc = actb[lane];
        const float4* arow = (const float4*)(haf + (size_t)b * 1024);
#pragma unroll 4
        for (int k4 = 0; k4 < 256; k4++) {
            float4 a4 = arow[k4];
            float4 w4 = *(const float4*)(actT4 + ((size_t)k4 * 64 + lane) * 4);
            acc += a4.x * w4.x + a4.y * w4.y + a4.z * w4.z + a4.w * w4.w;
        }
        float v = acc; int idx = lane;
#pragma unroll
        for (int off = 32; off; off >>= 1) {
            float ov = __shfl_xor(v, off);
            int   oi = __shfl_xor(idx, off);
            if (ov > v || (ov == v && oi < idx)) { v = ov; idx = oi; }
        }
        float e = expf(acc - v);
        float s = e;
#pragma unroll
        for (int off = 32; off; off >>= 1) s += __shfl_xor(s, off);
        out_acts[((size_t)b * 64 + tact) * 64 + lane] = e / s;
        if (lane == 0) aidx[b] = idx;
    } else {
        if (tts < 0) return;
        int b = (blk - 256) * 4 + w;
        const float* ur = u + (size_t)b * 512;
        float s = 0.0f;
#pragma unroll
        for (int q = 0; q < 8; q++) s = fmaf(ur[lane + q * 64], w2[lane + q * 64], s);
#pragma unroll
        for (int off = 32; off; off >>= 1) s += __shfl_xor(s, off);
        if (lane == 0) {
            float r = s + b2[0];
            out_ts[b * 64 + tts] = r;
            tsv[b] = r;
        }
    }
}

// ---------------- fp32 GEMM (setup only) ----------------
__global__ __launch_bounds__(256) void gemm_f32(
    const float* __restrict__ A0, const float* __restrict__ W0, float* __restrict__ C0,
    const float* __restrict__ A1, const float* __restrict__ W1, float* __restrict__ C1,
    int lda, int ldw, int ldc, int K, const float* __restrict__ bias, int relu)
{
    const float* Ap = blockIdx.z ? A1 : A0;
    const float* Wp = blockIdx.z ? W1 : W0;
    float*       Cp = blockIdx.z ? C1 : C0;
    __shared__ float As[16][128];
    __shared__ float Bs[16][64];
    const int tid = threadIdx.x;
    const int m0 = blockIdx.x * 128, n0 = blockIdx.y * 64;
    const int tx = tid & 7, ty = tid >> 3;
    const bool wal = (ldw & 3) == 0;
    float acc[4][8];
#pragma unroll
    for (int i = 0; i < 4; i++)
#pragma unroll
        for (int j = 0; j < 8; j++) acc[i][j] = 0.0f;

    for (int k0 = 0; k0 < K; k0 += 16) {
        __syncthreads();
#pragma unroll
        for (int q = 0; q < 2; q++) {
            int t2 = tid + q * 256;
            int kq = t2 & 3, m = t2 >> 2;
            float4 v = *(const float4*)(Ap + (size_t)(m0 + m) * lda + k0 + kq * 4);
            As[kq * 4 + 0][m] = v.x; As[kq * 4 + 1][m] = v.y;
            As[kq * 4 + 2][m] = v.z; As[kq * 4 + 3][m] = v.w;
        }
        {
            int kq = tid & 3, n = tid >> 2;
            const float* src = Wp + (size_t)(n0 + n) * ldw + k0 + kq * 4;
            float4 v;
            if (wal) v = *(const float4*)src;
            else { v.x = src[0]; v.y = src[1]; v.z = src[2]; v.w = src[3]; }
            Bs[kq * 4 + 0][n] = v.x; Bs[kq * 4 + 1][n] = v.y;
            Bs[kq * 4 + 2][n] = v.z; Bs[kq * 4 + 3][n] = v.w;
        }
        __syncthreads();
#pragma unroll
        for (int k = 0; k < 16; k++) {
            float a4[4], b8[8];
            *(float4*)a4 = *(const float4*)&As[k][ty * 4];
            *(float4*)(b8) = *(const float4*)&Bs[k][tx * 8];
            *(float4*)(b8 + 4) = *(const float4*)&Bs[k][tx * 8 + 4];
#pragma unroll
            for (int i = 0; i < 4; i++)
#pragma unroll
                for (int j = 0; j < 8; j++) acc[i][j] = fmaf(a4[i], b8[j], acc[i][j]);
        }
    }
#pragma unroll
    for (int i = 0; i < 4; i++) {
        int m = m0 + ty * 4 + i;
        float vb[8];
#pragma unroll
        for (int j = 0; j < 8; j++) {
            float v = acc[i][j];
            if (bias) v += bias[n0 + tx * 8 + j];
            if (relu) v = fmaxf(v, 0.0f);
            vb[j] = v;
        }
        float* dst = Cp + (size_t)m * ldc + n0 + tx * 8;
        *(float4*)dst = make_float4(vb[0], vb[1], vb[2], vb[3]);
        *(float4*)(dst + 4) = make_float4(vb[4], vb[5], vb[6], vb[7]);
    }
}

// ------------- setup kernels -------------
__global__ void extract_cols(const float* __restrict__ Wih, int ldw, int col0, int ncols,
                             float* __restrict__ E)
{
    int i = blockIdx.x * 256 + threadIdx.x;
    if (i >= ncols * 4096) return;
    int c = i % ncols, j = i / ncols;
    E[(size_t)c * 4096 + j] = Wih[(size_t)j * ldw + col0 + c];
}

__global__ void split_mat_h(const float* __restrict__ X,
                            unsigned short* __restrict__ hi, unsigned short* __restrict__ lo, int n)
{
    int i = blockIdx.x * 256 + threadIdx.x;
    if (i >= n) return;
    split_f16(X[i], hi[i], lo[i]);
}

// pack-transpose: out[((k>>2)*C + c)*4 + (k&3)] = W[c*K + k]
__global__ void transpose_pack(const float* __restrict__ W, int K, int C, float* __restrict__ out)
{
    int i = blockIdx.x * 256 + threadIdx.x;
    if (i >= C * K) return;
    int c = i / K, k = i - c * K;
    out[(((size_t)(k >> 2) * C + c) << 2) + (k & 3)] = W[i];
}

__global__ void init_state(float* __restrict__ cc, unsigned int* __restrict__ hilo,
                           float* __restrict__ tsv, int* __restrict__ aidx, int* __restrict__ ridx)
{
    int i = blockIdx.x * 256 + threadIdx.x;
    if (i < 3 * 1024 * 1024) cc[i] = 0.0f;
    if (i < 6 * 1024 * 1024) hilo[i] = 0u;          // 12M ushort of split state
    if (i < 1024) { tsv[i] = 0.0f; aidx[i] = 63; ridx[i] = 127; }
}

extern "C" void kernel_launch(void* const* d_in, const int* in_sizes, int n_in,
                              void* d_out, int out_size, void* d_ws, size_t ws_size,
                              hipStream_t stream)
{
    const float* z       = (const float*)d_in[0];
    const float* z2t_w   = (const float*)d_in[1];
    const float* z2t_b   = (const float*)d_in[2];
    const float* Wih_a   = (const float*)d_in[3];
    const float* Whh_a   = (const float*)d_in[4];
    const float* b_a     = (const float*)d_in[5];
    const float* Wih_r   = (const float*)d_in[6];
    const float* Whh_r   = (const float*)d_in[7];
    const float* b_r     = (const float*)d_in[8];
    const float* Wih_t   = (const float*)d_in[9];
    const float* Whh_t   = (const float*)d_in[10];
    const float* b_t     = (const float*)d_in[11];
    const float* e2act_w = (const float*)d_in[12];
    const float* e2act_b = (const float*)d_in[13];
    const float* e2res_w = (const float*)d_in[14];
    const float* e2res_b = (const float*)d_in[15];
    const float* e2ts_w1 = (const float*)d_in[16];
    const float* e2ts_b1 = (const float*)d_in[17];
    const float* e2ts_w2 = (const float*)d_in[18];
    const float* e2ts_b2 = (const float*)d_in[19];

    float* out_acts = (float*)d_out;                     // [1024][64][64]
    float* out_ts   = out_acts + (size_t)1024 * 64 * 64; // [1024][64]
    float* out_res  = out_ts + 1024 * 64;                // [1024][64][128]

    float* ws = (float*)d_ws;
    size_t off = 0;
    auto alloc = [&](size_t n) { float* p = ws + off; off += n; return p; };
    float* t_rec  = alloc((size_t)1024 * 512);
    float* base_a = alloc((size_t)1024 * 4096);
    float* base_r = alloc((size_t)1024 * 4096);
    float* base_t = alloc((size_t)1024 * 4096);
    float* Ea     = alloc((size_t)64 * 4096);
    float* Er_a   = alloc((size_t)64 * 4096);
    float* Er_r   = alloc((size_t)128 * 4096);
    float* Et_a   = alloc((size_t)64 * 4096);
    float* wtts   = alloc(4096);
    float* cc     = alloc((size_t)3 * 1024 * 1024);      // ca, cr, ct
    float* ca = cc, * cr = cc + 1048576, * ct = cc + 2097152;
    float* haf    = alloc((size_t)1024 * 1024);
    float* hrf    = alloc((size_t)1024 * 1024);
    float* u      = alloc((size_t)1024 * 512);
    float* tsv    = alloc(1024);
    int*   aidx   = (int*)alloc(1024);
    int*   ridx   = (int*)alloc(1024);
    float* actT4  = alloc((size_t)64 * 1024);
    float* resT4  = alloc((size_t)128 * 1024);
    // ping-pong split state: 12 x 1M ushort = 6M floats
    unsigned short* hilo = (unsigned short*)alloc((size_t)6 * 1024 * 1024);
    const size_t U = 1048576;
    unsigned short* haSp0[2] = {hilo,         hilo + U};
    unsigned short* haSp1[2] = {hilo + 2 * U, hilo + 3 * U};
    unsigned short* hrSp0[2] = {hilo + 4 * U, hilo + 5 * U};
    unsigned short* hrSp1[2] = {hilo + 6 * U, hilo + 7 * U};
    unsigned short* htSp0[2] = {hilo + 8 * U, hilo + 9 * U};
    unsigned short* htSp1[2] = {hilo + 10 * U, hilo + 11 * U};
    // split weights
    unsigned short* WA0 = (unsigned short*)alloc((size_t)2 * 1024 * 1024);
    unsigned short* WA1 = (unsigned short*)alloc((size_t)2 * 1024 * 1024);
    unsigned short* WR0 = (unsigned short*)alloc((size_t)2 * 1024 * 1024);
    unsigned short* WR1 = (unsigned short*)alloc((size_t)2 * 1024 * 1024);
    unsigned short* WT0 = (unsigned short*)alloc((size_t)2 * 1024 * 1024);
    unsigned short* WT1 = (unsigned short*)alloc((size_t)2 * 1024 * 1024);
    unsigned short* W10 = (unsigned short*)alloc((size_t)256 * 1024);
    unsigned short* W11 = (unsigned short*)alloc((size_t)256 * 1024);

    dim3 blk(256);
    init_state<<<(6 * 1024 * 1024 + 255) / 256, blk, 0, stream>>>(cc, (unsigned int*)hilo, tsv, aidx, ridx);

    // t_rec = relu(z @ z2t_w.T + z2t_b)
    gemm_f32<<<dim3(8, 8, 1), blk, 0, stream>>>(z, z2t_w, t_rec, z, z2t_w, t_rec,
                                                256, 256, 512, 256, z2t_b, 1);
    // base_* = t_rec @ Wih_*[:, :512].T + b_*
    gemm_f32<<<dim3(8, 64, 1), blk, 0, stream>>>(t_rec, Wih_a, base_a, t_rec, Wih_a, base_a,
                                                 512, 576, 4096, 512, b_a, 0);
    gemm_f32<<<dim3(8, 64, 1), blk, 0, stream>>>(t_rec, Wih_r, base_r, t_rec, Wih_r, base_r,
                                                 512, 704, 4096, 512, b_r, 0);
    gemm_f32<<<dim3(8, 64, 1), blk, 0, stream>>>(t_rec, Wih_t, base_t, t_rec, Wih_t, base_t,
                                                 512, 577, 4096, 512, b_t, 0);
    // one-hot column tables
    extract_cols<<<(64 * 4096 + 255) / 256, blk, 0, stream>>>(Wih_a, 576, 512, 64, Ea);
    extract_cols<<<(64 * 4096 + 255) / 256, blk, 0, stream>>>(Wih_r, 704, 512, 64, Er_a);
    extract_cols<<<(128 * 4096 + 255) / 256, blk, 0, stream>>>(Wih_r, 704, 576, 128, Er_r);
    extract_cols<<<(64 * 4096 + 255) / 256, blk, 0, stream>>>(Wih_t, 577, 512, 64, Et_a);
    extract_cols<<<(4096 + 255) / 256, blk, 0, stream>>>(Wih_t, 577, 576, 1, wtts);
    // head weight transposes
    transpose_pack<<<(64 * 1024 + 255) / 256, blk, 0, stream>>>(e2act_w, 1024, 64, actT4);
    transpose_pack<<<(128 * 1024 + 255) / 256, blk, 0, stream>>>(e2res_w, 1024, 128, resT4);
    // weight splits (fp16 hi/lo, lo scaled by 2^11)
    split_mat_h<<<(4194304 + 255) / 256, blk, 0, stream>>>(Whh_a, WA0, WA1, 4194304);
    split_mat_h<<<(4194304 + 255) / 256, blk, 0, stream>>>(Whh_r, WR0, WR1, 4194304);
    split_mat_h<<<(4194304 + 255) / 256, blk, 0, stream>>>(Whh_t, WT0, WT1, 4194304);
    split_mat_h<<<(524288 + 255) / 256, blk, 0, stream>>>(e2ts_w1, W10, W11, 524288);

    for (int t = 0; t < 64; t++) {
        int rd = t & 1, wr = rd ^ 1;
        step1<<<832, blk, 0, stream>>>(
            haSp0[rd], haSp1[rd], WA0, WA1, base_a, Ea, aidx,
            ca, haSp0[wr], haSp1[wr], haf,
            htSp0[rd], htSp1[rd], W10, W11, e2ts_b1, u,
            hrf, resT4, e2res_b, out_res, ridx, t, 0);
        heads<<<512, blk, 0, stream>>>(haf, actT4, e2act_b, out_acts, aidx, t,
                                       u, e2ts_w2, e2ts_b2, out_ts, tsv, t - 1);
        step3<<<512, blk, 0, stream>>>(
            hrSp0[rd], hrSp1[rd], WR0, WR1, base_r, Er_a, Er_r, aidx, ridx, tsv,
            cr, hrSp0[wr], hrSp1[wr], hrf,
            htSp0[rd], htSp1[rd], WT0, WT1, base_t, Et_a, wtts,
            ct, htSp0[wr], htSp1[wr]);
    }
    // tail: u(63) from ht(63) (buffers at index 64&1=0), res(63), ts(63)
    step1<<<320, blk, 0, stream>>>(
        haSp0[0], haSp1[0], WA0, WA1, base_a, Ea, aidx,
        ca, haSp0[1], haSp1[1], haf,
        htSp0[0], htSp1[0], W10, W11, e2ts_b1, u,
        hrf, resT4, e2res_b, out_res, ridx, 64, 512);
    heads<<<512, blk, 0, stream>>>(haf, actT4, e2act_b, out_acts, aidx, -1,
                                   u, e2ts_w2, e2ts_b2, out_ts, tsv, 63);
}

// Round 2
// 14512.645 us; speedup vs baseline: 1.1406x; 1.0133x over previous
//
#include <hip/hip_runtime.h>
#include <math.h>

// Decoder: B=1024, Z=256, TDIM=512, CF=1024, A=64, R=128, T=64
// R9: step3 restructured to step1's proven tile shape: 128x64 tiles (4 gates x 16 j),
//     wave==gate, 48KB LDS double-buffer (3 blocks/CU vs 64KB's 2), 6 GLDS/phase,
//     vmcnt(6). 1024 blocks = 2 cells x 64 j-tiles x 8 m-tiles, XCD-swizzled so the
//     8 m-blocks sharing a weight panel land on one XCD. K-order + hi/lo MFMA
//     sequence unchanged -> bit-identical numerics vs R8. step1/heads/setup unchanged.

__device__ __forceinline__ float sigf(float x) { return 1.0f / (1.0f + expf(-x)); }

typedef __attribute__((ext_vector_type(8))) _Float16 f16x8;
typedef __attribute__((ext_vector_type(4))) float f32x4;

__device__ __forceinline__ void split_f16(float x, unsigned short& hi, unsigned short& lo) {
    _Float16 h = (_Float16)x;                   // RNE f32->f16
    float r = (x - (float)h) * 2048.0f;         // exact
    _Float16 l = (_Float16)r;
    hi = __builtin_bit_cast(unsigned short, h);
    lo = __builtin_bit_cast(unsigned short, l);
}

#define GLDS(gp, lp) __builtin_amdgcn_global_load_lds( \
    (const __attribute__((address_space(1))) void*)(gp), \
    (__attribute__((address_space(3))) void*)(lp), 16, 0, 0)

// ---------------- step1: a-cell GEMM+LSTM | u GEMM | res head ----------------
// a: 128x64 tiles (64 N = 4 gates x 16 j), 4 waves (wm=wave, 32 rows each), ni=gate.
// u: 128x64 tiles over N=512.
// L<512: a (XCD-swizzled); 512..575: u; 576..831: res head for step t-1.
__global__ __launch_bounds__(256) void step1(
    const unsigned short* __restrict__ Ah, const unsigned short* __restrict__ Al,
    const unsigned short* __restrict__ WA0, const unsigned short* __restrict__ WA1,
    const float* __restrict__ base_a, const float* __restrict__ Ea, const int* __restrict__ aidx,
    float* __restrict__ ca, unsigned short* __restrict__ oAh, unsigned short* __restrict__ oAl,
    float* __restrict__ haf,
    const unsigned short* __restrict__ Th, const unsigned short* __restrict__ Tl,
    const unsigned short* __restrict__ W10, const unsigned short* __restrict__ W11,
    const float* __restrict__ b1, float* __restrict__ u,
    const float* __restrict__ hrf, const float* __restrict__ resT4, const float* __restrict__ resb,
    float* __restrict__ out_res, int* __restrict__ ridx, int t, int Loff)
{
    int L = blockIdx.x + Loff;
    if (L >= 576) {
        // ---- res head for step t-1 ----
        if (t == 0) return;
        int lane = threadIdx.x & 63, w = threadIdx.x >> 6;
        int b = (L - 576) * 4 + w;
        float acc0 = resb[lane], acc1 = resb[lane + 64];
        const float4* arow = (const float4*)(hrf + (size_t)b * 1024);
#pragma unroll 4
        for (int k4 = 0; k4 < 256; k4++) {
            float4 a4 = arow[k4];
            float4 w40 = *(const float4*)(resT4 + ((size_t)k4 * 128 + lane) * 4);
            float4 w41 = *(const float4*)(resT4 + ((size_t)k4 * 128 + lane + 64) * 4);
            acc0 += a4.x * w40.x + a4.y * w40.y + a4.z * w40.z + a4.w * w40.w;
            acc1 += a4.x * w41.x + a4.y * w41.y + a4.z * w41.z + a4.w * w41.w;
        }
        float v = acc0; int idx = lane;
        if (acc1 > v) { v = acc1; idx = lane + 64; }
#pragma unroll
        for (int off = 32; off; off >>= 1) {
            float ov = __shfl_xor(v, off);
            int   oi = __shfl_xor(idx, off);
            if (ov > v || (ov == v && oi < idx)) { v = ov; idx = oi; }
        }
        float e0 = expf(acc0 - v), e1 = expf(acc1 - v);
        float s = e0 + e1;
#pragma unroll
        for (int off = 32; off; off >>= 1) s += __shfl_xor(s, off);
        float* dst = out_res + ((size_t)b * 64 + (t - 1)) * 128;
        dst[lane] = e0 / s; dst[lane + 64] = e1 / s;
        if (lane == 0) ridx[b] = idx;
        return;
    }

    // ---- GEMM part (a or u) ----
    // 48KB LDS: 2 bufs x 12288 ushorts {Ah[0,4096) Al[4096,8192) Bh[8192,10240) Bl[10240,12288)}
    __shared__ unsigned short lds[24576];
    const unsigned short *pAh, *pAl, *pWh, *pWl;
    int x, jy; bool isA;
    if (L < 512) {
        isA = true;
        int xcd = L & 7, idx = L >> 3;
        jy = xcd * 8 + (idx >> 3);       // j-tile 0..63 (j0 = jy*16)
        x = idx & 7;
        pAh = Ah; pAl = Al; pWh = WA0; pWl = WA1;
    } else {
        isA = false;
        int t2 = L - 512;
        x = t2 & 7; jy = t2 >> 3;        // u: n0 = jy*64
        pAh = Th; pAl = Tl; pWh = W10; pWl = W11;
    }
    const int tid = threadIdx.x, wave = tid >> 6, lane = tid & 63;
    const int lrow = lane & 15, lq = lane >> 4;
    const int m0 = x * 128;

    f32x4 acch[2][4], accl[2][4];
#pragma unroll
    for (int i = 0; i < 2; i++)
#pragma unroll
        for (int j = 0; j < 4; j++) {
            acch[i][j] = (f32x4){0.f, 0.f, 0.f, 0.f};
            accl[i][j] = (f32x4){0.f, 0.f, 0.f, 0.f};
        }

    const int nrow = isA ? (wave * 1024 + jy * 16 + lrow) : (jy * 64 + wave * 16 + lrow);

    // stage one BK=32 chunk into buffer p: 6 GLDS per wave (4 A-blocks + 2 B)
    auto STAGE = [&](int it, int p) {
        int k = it * 32 + lq * 8;
        unsigned short* bp = &lds[p * 12288];
#pragma unroll
        for (int ss = 0; ss < 2; ss++) {
            int s = wave * 2 + ss;
            int mrow = m0 + s * 16 + lrow;
            GLDS(pAh + (size_t)mrow * 1024 + k, bp + s * 512);
            GLDS(pAl + (size_t)mrow * 1024 + k, bp + 4096 + s * 512);
        }
        GLDS(pWh + (size_t)nrow * 1024 + k, bp + 8192 + wave * 512);
        GLDS(pWl + (size_t)nrow * 1024 + k, bp + 10240 + wave * 512);
    };
    // consume buffer p: 12 ds_read_b128 + 24 MFMA
    auto COMPUTE = [&](int p) {
        unsigned short* bp = &lds[p * 12288];
        f16x8 ah[2], al[2], bh[4], bl[4];
#pragma unroll
        for (int mi = 0; mi < 2; mi++) {
            ah[mi] = *(const f16x8*)(bp + (wave * 2 + mi) * 512 + lane * 8);
            al[mi] = *(const f16x8*)(bp + 4096 + (wave * 2 + mi) * 512 + lane * 8);
        }
#pragma unroll
        for (int ni = 0; ni < 4; ni++) {
            bh[ni] = *(const f16x8*)(bp + 8192 + ni * 512 + lane * 8);
            bl[ni] = *(const f16x8*)(bp + 10240 + ni * 512 + lane * 8);
        }
#pragma unroll
        for (int mi = 0; mi < 2; mi++)
#pragma unroll
            for (int ni = 0; ni < 4; ni++) {
                acch[mi][ni] = __builtin_amdgcn_mfma_f32_16x16x32_f16(ah[mi], bh[ni], acch[mi][ni], 0, 0, 0);
                accl[mi][ni] = __builtin_amdgcn_mfma_f32_16x16x32_f16(al[mi], bh[ni], accl[mi][ni], 0, 0, 0);
                accl[mi][ni] = __builtin_amdgcn_mfma_f32_16x16x32_f16(ah[mi], bl[ni], accl[mi][ni], 0, 0, 0);
            }
    };

    STAGE(0, 0);
    for (int it = 0; it < 31; ++it) {
        int cur = it & 1;
        STAGE(it + 1, cur ^ 1);                          // 6 GLDS in flight across compute
        asm volatile("s_waitcnt vmcnt(6)" ::: "memory"); // cur buffer's 6 complete (in-order)
        __builtin_amdgcn_s_barrier();
        __builtin_amdgcn_sched_barrier(0);
        COMPUTE(cur);
        __builtin_amdgcn_sched_barrier(0);
        __builtin_amdgcn_s_barrier();                    // reads of cur done before overwrite
    }
    asm volatile("s_waitcnt vmcnt(0)" ::: "memory");
    __builtin_amdgcn_s_barrier();
    __builtin_amdgcn_sched_barrier(0);
    COMPUTE(1);

    const float s_lo = 1.0f / 2048.0f;
    if (isA) {
        // fused LSTM-a epilogue: ni == gate, thread-local
        int j = jy * 16 + lrow;
#pragma unroll
        for (int mi = 0; mi < 2; mi++)
#pragma unroll
            for (int r = 0; r < 4; r++) {
                int row = m0 + wave * 32 + mi * 16 + lq * 4 + r;
                size_t rb = (size_t)row * 4096 + j;
                const float* e1 = Ea + (size_t)aidx[row] * 4096 + j;
                float gi = acch[mi][0][r] + accl[mi][0][r] * s_lo + base_a[rb]        + e1[0];
                float gf = acch[mi][1][r] + accl[mi][1][r] * s_lo + base_a[rb + 1024] + e1[1024];
                float gg = acch[mi][2][r] + accl[mi][2][r] * s_lo + base_a[rb + 2048] + e1[2048];
                float go = acch[mi][3][r] + accl[mi][3][r] * s_lo + base_a[rb + 3072] + e1[3072];
                size_t ci = (size_t)row * 1024 + j;
                float cn = sigf(gf) * ca[ci] + sigf(gi) * tanhf(gg);
                ca[ci] = cn;
                float hn = sigf(go) * tanhf(cn);
                haf[ci] = hn;
                split_f16(hn, oAh[ci], oAl[ci]);
            }
    } else {
        // u = relu(ht @ W1^T + b1)
#pragma unroll
        for (int mi = 0; mi < 2; mi++)
#pragma unroll
            for (int ni = 0; ni < 4; ni++) {
                int col = jy * 64 + ni * 16 + lrow;
                float bv = b1[col];
#pragma unroll
                for (int r = 0; r < 4; r++) {
                    int row = m0 + wave * 32 + mi * 16 + lq * 4 + r;
                    float v = acch[mi][ni][r] + accl[mi][ni][r] * s_lo + bv;
                    u[(size_t)row * 512 + col] = fmaxf(v, 0.0f);
                }
            }
    }
}

// ---------------- step3: r & t cell GEMM + fused LSTM epilogue ----------------
// R9: 128x64 tiles (64 N = 4 gates x 16 j), wave==gate, 48KB LDS (3 blocks/CU).
// 1024 blocks = 8 m-tiles x 128 (cell,j-tile) groups; XCD-swizzled so the 8 m-blocks
// sharing a weight panel land on one XCD (cell r -> XCD 0-3, cell t -> XCD 4-7).
__global__ __launch_bounds__(256) void step3(
    const unsigned short* __restrict__ Rh, const unsigned short* __restrict__ Rl,
    const unsigned short* __restrict__ WR0, const unsigned short* __restrict__ WR1,
    const float* __restrict__ base_r, const float* __restrict__ Er_a, const float* __restrict__ Er_r,
    const int* __restrict__ aidx, const int* __restrict__ ridx, const float* __restrict__ tsv,
    float* __restrict__ cr, unsigned short* __restrict__ oRh, unsigned short* __restrict__ oRl,
    float* __restrict__ hrf,
    const unsigned short* __restrict__ Th, const unsigned short* __restrict__ Tl,
    const unsigned short* __restrict__ WT0, const unsigned short* __restrict__ WT1,
    const float* __restrict__ base_t, const float* __restrict__ Et_a, const float* __restrict__ wtts,
    float* __restrict__ ct, unsigned short* __restrict__ oTh, unsigned short* __restrict__ oTl)
{
    // 48KB LDS: 2 bufs x 12288 ushorts {Ah[0,4096) Al[4096,8192) Bh[8192,10240) Bl[10240,12288)}
    __shared__ unsigned short lds[24576];
    int L = blockIdx.x;
    int xcd = L & 7, idx = L >> 3;
    int g = xcd * 16 + (idx >> 3);           // 128 (z, jy) groups
    int x = idx & 7;
    int z = g >> 6, jy = g & 63;
    const unsigned short* pAh = z ? Th : Rh;
    const unsigned short* pAl = z ? Tl : Rl;
    const unsigned short* pWh = z ? WT0 : WR0;
    const unsigned short* pWl = z ? WT1 : WR1;

    const int tid = threadIdx.x, wave = tid >> 6, lane = tid & 63;
    const int lrow = lane & 15, lq = lane >> 4;
    const int m0 = x * 128;

    f32x4 acch[2][4], accl[2][4];
#pragma unroll
    for (int i = 0; i < 2; i++)
#pragma unroll
        for (int j = 0; j < 4; j++) {
            acch[i][j] = (f32x4){0.f, 0.f, 0.f, 0.f};
            accl[i][j] = (f32x4){0.f, 0.f, 0.f, 0.f};
        }

    const int nrow = wave * 1024 + jy * 16 + lrow;   // wave == gate

    // stage one BK=32 chunk into buffer p: 6 GLDS per wave (4 A-blocks + 2 B)
    auto STAGE = [&](int it, int p) {
        int k = it * 32 + lq * 8;
        unsigned short* bp = &lds[p * 12288];
#pragma unroll
        for (int ss = 0; ss < 2; ss++) {
            int s = wave * 2 + ss;
            int mrow = m0 + s * 16 + lrow;
            GLDS(pAh + (size_t)mrow * 1024 + k, bp + s * 512);
            GLDS(pAl + (size_t)mrow * 1024 + k, bp + 4096 + s * 512);
        }
        GLDS(pWh + (size_t)nrow * 1024 + k, bp + 8192 + wave * 512);
        GLDS(pWl + (size_t)nrow * 1024 + k, bp + 10240 + wave * 512);
    };
    // consume buffer p: 12 ds_read_b128 + 24 MFMA
    auto COMPUTE = [&](int p) {
        unsigned short* bp = &lds[p * 12288];
        f16x8 ah[2], al[2], bh[4], bl[4];
#pragma unroll
        for (int mi = 0; mi < 2; mi++) {
            ah[mi] = *(const f16x8*)(bp + (wave * 2 + mi) * 512 + lane * 8);
            al[mi] = *(const f16x8*)(bp + 4096 + (wave * 2 + mi) * 512 + lane * 8);
        }
#pragma unroll
        for (int ni = 0; ni < 4; ni++) {
            bh[ni] = *(const f16x8*)(bp + 8192 + ni * 512 + lane * 8);
            bl[ni] = *(const f16x8*)(bp + 10240 + ni * 512 + lane * 8);
        }
#pragma unroll
        for (int mi = 0; mi < 2; mi++)
#pragma unroll
            for (int ni = 0; ni < 4; ni++) {
                acch[mi][ni] = __builtin_amdgcn_mfma_f32_16x16x32_f16(ah[mi], bh[ni], acch[mi][ni], 0, 0, 0);
                accl[mi][ni] = __builtin_amdgcn_mfma_f32_16x16x32_f16(al[mi], bh[ni], accl[mi][ni], 0, 0, 0);
                accl[mi][ni] = __builtin_amdgcn_mfma_f32_16x16x32_f16(ah[mi], bl[ni], accl[mi][ni], 0, 0, 0);
            }
    };

    STAGE(0, 0);
    for (int it = 0; it < 31; ++it) {
        int cur = it & 1;
        STAGE(it + 1, cur ^ 1);                          // 6 GLDS in flight across compute
        asm volatile("s_waitcnt vmcnt(6)" ::: "memory"); // cur buffer's 6 complete (in-order)
        __builtin_amdgcn_s_barrier();
        __builtin_amdgcn_sched_barrier(0);
        COMPUTE(cur);
        __builtin_amdgcn_sched_barrier(0);
        __builtin_amdgcn_s_barrier();                    // reads of cur done before overwrite
    }
    asm volatile("s_waitcnt vmcnt(0)" ::: "memory");
    __builtin_amdgcn_s_barrier();
    __builtin_amdgcn_sched_barrier(0);
    COMPUTE(1);

    const float s_lo = 1.0f / 2048.0f;
    const int j = jy * 16 + lrow;
    if (z == 0) {
        // cell r
#pragma unroll
        for (int mi = 0; mi < 2; mi++)
#pragma unroll
            for (int r = 0; r < 4; r++) {
                int row = m0 + wave * 32 + mi * 16 + lq * 4 + r;
                size_t rb = (size_t)row * 4096 + j;
                const float* e1 = Er_a + (size_t)aidx[row] * 4096 + j;
                const float* e2 = Er_r + (size_t)ridx[row] * 4096 + j;
                float gi = acch[mi][0][r] + accl[mi][0][r] * s_lo + base_r[rb]        + e1[0]    + e2[0];
                float gf = acch[mi][1][r] + accl[mi][1][r] * s_lo + base_r[rb + 1024] + e1[1024] + e2[1024];
                float gg = acch[mi][2][r] + accl[mi][2][r] * s_lo + base_r[rb + 2048] + e1[2048] + e2[2048];
                float go = acch[mi][3][r] + accl[mi][3][r] * s_lo + base_r[rb + 3072] + e1[3072] + e2[3072];
                size_t ci = (size_t)row * 1024 + j;
                float cn = sigf(gf) * cr[ci] + sigf(gi) * tanhf(gg);
                cr[ci] = cn;
                float hn = sigf(go) * tanhf(cn);
                hrf[ci] = hn;
                split_f16(hn, oRh[ci], oRl[ci]);
            }
    } else {
        // cell t
#pragma unroll
        for (int mi = 0; mi < 2; mi++)
#pragma unroll
            for (int r = 0; r < 4; r++) {
                int row = m0 + wave * 32 + mi * 16 + lq * 4 + r;
                size_t rb = (size_t)row * 4096 + j;
                const float* e1 = Et_a + (size_t)aidx[row] * 4096 + j;
                float tv = tsv[row];
                float gi = acch[mi][0][r] + accl[mi][0][r] * s_lo + base_t[rb]        + e1[0];
                float gf = acch[mi][1][r] + accl[mi][1][r] * s_lo + base_t[rb + 1024] + e1[1024];
                float gg = acch[mi][2][r] + accl[mi][2][r] * s_lo + base_t[rb + 2048] + e1[2048];
                float go = acch[mi][3][r] + accl[mi][3][r] * s_lo + base_t[rb + 3072] + e1[3072];
                gi = fmaf(tv, wtts[j], gi);        gf = fmaf(tv, wtts[j + 1024], gf);
                gg = fmaf(tv, wtts[j + 2048], gg); go = fmaf(tv, wtts[j + 3072], go);
                size_t ci = (size_t)row * 1024 + j;
                float cn = sigf(gf) * ct[ci] + sigf(gi) * tanhf(gg);
                ct[ci] = cn;
                float hn = sigf(go) * tanhf(cn);
                split_f16(hn, oTh[ci], oTl[ci]);
            }
    }
}

// ---------------- heads: act softmax/argmax (blocks 0..255) + ts_final (256..511) ----------------
__global__ __launch_bounds__(256) void heads(
    const float* __restrict__ haf, const float* __restrict__ actT4, const float* __restrict__ actb,
    float* __restrict__ out_acts, int* __restrict__ aidx, int tact,
    const float* __restrict__ u, const float* __restrict__ w2, const float* __restrict__ b2,
    float* __restrict__ out_ts, float* __restrict__ tsv, int tts)
{
    int blk = blockIdx.x;
    int lane = threadIdx.x & 63, w = threadIdx.x >> 6;
    if (blk < 256) {
        if (tact < 0) return;
        int b = blk * 4 + w;
        float acc = actb[lane];
        const float4* arow = (const float4*)(haf + (size_t)b * 1024);
#pragma unroll 4
        for (int k4 = 0; k4 < 256; k4++) {
            float4 a4 = arow[k4];
            float4 w4 = *(const float4*)(actT4 + ((size_t)k4 * 64 + lane) * 4);
            acc += a4.x * w4.x + a4.y * w4.y + a4.z * w4.z + a4.w * w4.w;
        }
        float v = acc; int idx = lane;
#pragma unroll
        for (int off = 32; off; off >>= 1) {
            float ov = __shfl_xor(v, off);
            int   oi = __shfl_xor(idx, off);
            if (ov > v || (ov == v && oi < idx)) { v = ov; idx = oi; }
        }
        float e = expf(acc - v);
        float s = e;
#pragma unroll
        for (int off = 32; off; off >>= 1) s += __shfl_xor(s, off);
        out_acts[((size_t)b * 64 + tact) * 64 + lane] = e / s;
        if (lane == 0) aidx[b] = idx;
    } else {
        if (tts < 0) return;
        int b = (blk - 256) * 4 + w;
        const float* ur = u + (size_t)b * 512;
        float s = 0.0f;
#pragma unroll
        for (int q = 0; q < 8; q++) s = fmaf(ur[lane + q * 64], w2[lane + q * 64], s);
#pragma unroll
        for (int off = 32; off; off >>= 1) s += __shfl_xor(s, off);
        if (lane == 0) {
            float r = s + b2[0];
            out_ts[b * 64 + tts] = r;
            tsv[b] = r;
        }
    }
}

// ---------------- fp32 GEMM (setup only) ----------------
__global__ __launch_bounds__(256) void gemm_f32(
    const float* __restrict__ A0, const float* __restrict__ W0, float* __restrict__ C0,
    const float* __restrict__ A1, const float* __restrict__ W1, float* __restrict__ C1,
    int lda, int ldw, int ldc, int K, const float* __restrict__ bias, int relu)
{
    const float* Ap = blockIdx.z ? A1 : A0;
    const float* Wp = blockIdx.z ? W1 : W0;
    float*       Cp = blockIdx.z ? C1 : C0;
    __shared__ float As[16][128];
    __shared__ float Bs[16][64];
    const int tid = threadIdx.x;
    const int m0 = blockIdx.x * 128, n0 = blockIdx.y * 64;
    const int tx = tid & 7, ty = tid >> 3;
    const bool wal = (ldw & 3) == 0;
    float acc[4][8];
#pragma unroll
    for (int i = 0; i < 4; i++)
#pragma unroll
        for (int j = 0; j < 8; j++) acc[i][j] = 0.0f;

    for (int k0 = 0; k0 < K; k0 += 16) {
        __syncthreads();
#pragma unroll
        for (int q = 0; q < 2; q++) {
            int t2 = tid + q * 256;
            int kq = t2 & 3, m = t2 >> 2;
            float4 v = *(const float4*)(Ap + (size_t)(m0 + m) * lda + k0 + kq * 4);
            As[kq * 4 + 0][m] = v.x; As[kq * 4 + 1][m] = v.y;
            As[kq * 4 + 2][m] = v.z; As[kq * 4 + 3][m] = v.w;
        }
        {
            int kq = tid & 3, n = tid >> 2;
            const float* src = Wp + (size_t)(n0 + n) * ldw + k0 + kq * 4;
            float4 v;
            if (wal) v = *(const float4*)src;
            else { v.x = src[0]; v.y = src[1]; v.z = src[2]; v.w = src[3]; }
            Bs[kq * 4 + 0][n] = v.x; Bs[kq * 4 + 1][n] = v.y;
            Bs[kq * 4 + 2][n] = v.z; Bs[kq * 4 + 3][n] = v.w;
        }
        __syncthreads();
#pragma unroll
        for (int k = 0; k < 16; k++) {
            float a4[4], b8[8];
            *(float4*)a4 = *(const float4*)&As[k][ty * 4];
            *(float4*)(b8) = *(const float4*)&Bs[k][tx * 8];
            *(float4*)(b8 + 4) = *(const float4*)&Bs[k][tx * 8 + 4];
#pragma unroll
            for (int i = 0; i < 4; i++)
#pragma unroll
                for (int j = 0; j < 8; j++) acc[i][j] = fmaf(a4[i], b8[j], acc[i][j]);
        }
    }
#pragma unroll
    for (int i = 0; i < 4; i++) {
        int m = m0 + ty * 4 + i;
        float vb[8];
#pragma unroll
        for (int j = 0; j < 8; j++) {
            float v = acc[i][j];
            if (bias) v += bias[n0 + tx * 8 + j];
            if (relu) v = fmaxf(v, 0.0f);
            vb[j] = v;
        }
        float* dst = Cp + (size_t)m * ldc + n0 + tx * 8;
        *(float4*)dst = make_float4(vb[0], vb[1], vb[2], vb[3]);
        *(float4*)(dst + 4) = make_float4(vb[4], vb[5], vb[6], vb[7]);
    }
}

// ------------- setup kernels -------------
__global__ void extract_cols(const float* __restrict__ Wih, int ldw, int col0, int ncols,
                             float* __restrict__ E)
{
    int i = blockIdx.x * 256 + threadIdx.x;
    if (i >= ncols * 4096) return;
    int c = i % ncols, j = i / ncols;
    E[(size_t)c * 4096 + j] = Wih[(size_t)j * ldw + col0 + c];
}

__global__ void split_mat_h(const float* __restrict__ X,
                            unsigned short* __restrict__ hi, unsigned short* __restrict__ lo, int n)
{
    int i = blockIdx.x * 256 + threadIdx.x;
    if (i >= n) return;
    split_f16(X[i], hi[i], lo[i]);
}

// pack-transpose: out[((k>>2)*C + c)*4 + (k&3)] = W[c*K + k]
__global__ void transpose_pack(const float* __restrict__ W, int K, int C, float* __restrict__ out)
{
    int i = blockIdx.x * 256 + threadIdx.x;
    if (i >= C * K) return;
    int c = i / K, k = i - c * K;
    out[(((size_t)(k >> 2) * C + c) << 2) + (k & 3)] = W[i];
}

__global__ void init_state(float* __restrict__ cc, unsigned int* __restrict__ hilo,
                           float* __restrict__ tsv, int* __restrict__ aidx, int* __restrict__ ridx)
{
    int i = blockIdx.x * 256 + threadIdx.x;
    if (i < 3 * 1024 * 1024) cc[i] = 0.0f;
    if (i < 6 * 1024 * 1024) hilo[i] = 0u;          // 12M ushort of split state
    if (i < 1024) { tsv[i] = 0.0f; aidx[i] = 63; ridx[i] = 127; }
}

extern "C" void kernel_launch(void* const* d_in, const int* in_sizes, int n_in,
                              void* d_out, int out_size, void* d_ws, size_t ws_size,
                              hipStream_t stream)
{
    const float* z       = (const float*)d_in[0];
    const float* z2t_w   = (const float*)d_in[1];
    const float* z2t_b   = (const float*)d_in[2];
    const float* Wih_a   = (const float*)d_in[3];
    const float* Whh_a   = (const float*)d_in[4];
    const float* b_a     = (const float*)d_in[5];
    const float* Wih_r   = (const float*)d_in[6];
    const float* Whh_r   = (const float*)d_in[7];
    const float* b_r     = (const float*)d_in[8];
    const float* Wih_t   = (const float*)d_in[9];
    const float* Whh_t   = (const float*)d_in[10];
    const float* b_t     = (const float*)d_in[11];
    const float* e2act_w = (const float*)d_in[12];
    const float* e2act_b = (const float*)d_in[13];
    const float* e2res_w = (const float*)d_in[14];
    const float* e2res_b = (const float*)d_in[15];
    const float* e2ts_w1 = (const float*)d_in[16];
    const float* e2ts_b1 = (const float*)d_in[17];
    const float* e2ts_w2 = (const float*)d_in[18];
    const float* e2ts_b2 = (const float*)d_in[19];

    float* out_acts = (float*)d_out;                     // [1024][64][64]
    float* out_ts   = out_acts + (size_t)1024 * 64 * 64; // [1024][64]
    float* out_res  = out_ts + 1024 * 64;                // [1024][64][128]

    float* ws = (float*)d_ws;
    size_t off = 0;
    auto alloc = [&](size_t n) { float* p = ws + off; off += n; return p; };
    float* t_rec  = alloc((size_t)1024 * 512);
    float* base_a = alloc((size_t)1024 * 4096);
    float* base_r = alloc((size_t)1024 * 4096);
    float* base_t = alloc((size_t)1024 * 4096);
    float* Ea     = alloc((size_t)64 * 4096);
    float* Er_a   = alloc((size_t)64 * 4096);
    float* Er_r   = alloc((size_t)128 * 4096);
    float* Et_a   = alloc((size_t)64 * 4096);
    float* wtts   = alloc(4096);
    float* cc     = alloc((size_t)3 * 1024 * 1024);      // ca, cr, ct
    float* ca = cc, * cr = cc + 1048576, * ct = cc + 2097152;
    float* haf    = alloc((size_t)1024 * 1024);
    float* hrf    = alloc((size_t)1024 * 1024);
    float* u      = alloc((size_t)1024 * 512);
    float* tsv    = alloc(1024);
    int*   aidx   = (int*)alloc(1024);
    int*   ridx   = (int*)alloc(1024);
    float* actT4  = alloc((size_t)64 * 1024);
    float* resT4  = alloc((size_t)128 * 1024);
    // ping-pong split state: 12 x 1M ushort = 6M floats
    unsigned short* hilo = (unsigned short*)alloc((size_t)6 * 1024 * 1024);
    const size_t U = 1048576;
    unsigned short* haSp0[2] = {hilo,         hilo + U};
    unsigned short* haSp1[2] = {hilo + 2 * U, hilo + 3 * U};
    unsigned short* hrSp0[2] = {hilo + 4 * U, hilo + 5 * U};
    unsigned short* hrSp1[2] = {hilo + 6 * U, hilo + 7 * U};
    unsigned short* htSp0[2] = {hilo + 8 * U, hilo + 9 * U};
    unsigned short* htSp1[2] = {hilo + 10 * U, hilo + 11 * U};
    // split weights
    unsigned short* WA0 = (unsigned short*)alloc((size_t)2 * 1024 * 1024);
    unsigned short* WA1 = (unsigned short*)alloc((size_t)2 * 1024 * 1024);
    unsigned short* WR0 = (unsigned short*)alloc((size_t)2 * 1024 * 1024);
    unsigned short* WR1 = (unsigned short*)alloc((size_t)2 * 1024 * 1024);
    unsigned short* WT0 = (unsigned short*)alloc((size_t)2 * 1024 * 1024);
    unsigned short* WT1 = (unsigned short*)alloc((size_t)2 * 1024 * 1024);
    unsigned short* W10 = (unsigned short*)alloc((size_t)256 * 1024);
    unsigned short* W11 = (unsigned short*)alloc((size_t)256 * 1024);

    dim3 blk(256);
    init_state<<<(6 * 1024 * 1024 + 255) / 256, blk, 0, stream>>>(cc, (unsigned int*)hilo, tsv, aidx, ridx);

    // t_rec = relu(z @ z2t_w.T + z2t_b)
    gemm_f32<<<dim3(8, 8, 1), blk, 0, stream>>>(z, z2t_w, t_rec, z, z2t_w, t_rec,
                                                256, 256, 512, 256, z2t_b, 1);
    // base_* = t_rec @ Wih_*[:, :512].T + b_*
    gemm_f32<<<dim3(8, 64, 1), blk, 0, stream>>>(t_rec, Wih_a, base_a, t_rec, Wih_a, base_a,
                                                 512, 576, 4096, 512, b_a, 0);
    gemm_f32<<<dim3(8, 64, 1), blk, 0, stream>>>(t_rec, Wih_r, base_r, t_rec, Wih_r, base_r,
                                                 512, 704, 4096, 512, b_r, 0);
    gemm_f32<<<dim3(8, 64, 1), blk, 0, stream>>>(t_rec, Wih_t, base_t, t_rec, Wih_t, base_t,
                                                 512, 577, 4096, 512, b_t, 0);
    // one-hot column tables
    extract_cols<<<(64 * 4096 + 255) / 256, blk, 0, stream>>>(Wih_a, 576, 512, 64, Ea);
    extract_cols<<<(64 * 4096 + 255) / 256, blk, 0, stream>>>(Wih_r, 704, 512, 64, Er_a);
    extract_cols<<<(128 * 4096 + 255) / 256, blk, 0, stream>>>(Wih_r, 704, 576, 128, Er_r);
    extract_cols<<<(64 * 4096 + 255) / 256, blk, 0, stream>>>(Wih_t, 577, 512, 64, Et_a);
    extract_cols<<<(4096 + 255) / 256, blk, 0, stream>>>(Wih_t, 577, 576, 1, wtts);
    // head weight transposes
    transpose_pack<<<(64 * 1024 + 255) / 256, blk, 0, stream>>>(e2act_w, 1024, 64, actT4);
    transpose_pack<<<(128 * 1024 + 255) / 256, blk, 0, stream>>>(e2res_w, 1024, 128, resT4);
    // weight splits (fp16 hi/lo, lo scaled by 2^11)
    split_mat_h<<<(4194304 + 255) / 256, blk, 0, stream>>>(Whh_a, WA0, WA1, 4194304);
    split_mat_h<<<(4194304 + 255) / 256, blk, 0, stream>>>(Whh_r, WR0, WR1, 4194304);
    split_mat_h<<<(4194304 + 255) / 256, blk, 0, stream>>>(Whh_t, WT0, WT1, 4194304);
    split_mat_h<<<(524288 + 255) / 256, blk, 0, stream>>>(e2ts_w1, W10, W11, 524288);

    for (int t = 0; t < 64; t++) {
        int rd = t & 1, wr = rd ^ 1;
        step1<<<832, blk, 0, stream>>>(
            haSp0[rd], haSp1[rd], WA0, WA1, base_a, Ea, aidx,
            ca, haSp0[wr], haSp1[wr], haf,
            htSp0[rd], htSp1[rd], W10, W11, e2ts_b1, u,
            hrf, resT4, e2res_b, out_res, ridx, t, 0);
        heads<<<512, blk, 0, stream>>>(haf, actT4, e2act_b, out_acts, aidx, t,
                                       u, e2ts_w2, e2ts_b2, out_ts, tsv, t - 1);
        step3<<<1024, blk, 0, stream>>>(
            hrSp0[rd], hrSp1[rd], WR0, WR1, base_r, Er_a, Er_r, aidx, ridx, tsv,
            cr, hrSp0[wr], hrSp1[wr], hrf,
            htSp0[rd], htSp1[rd], WT0, WT1, base_t, Et_a, wtts,
            ct, htSp0[wr], htSp1[wr]);
    }
    // tail: u(63) from ht(63) (buffers at index 64&1=0), res(63), ts(63)
    step1<<<320, blk, 0, stream>>>(
        haSp0[0], haSp1[0], WA0, WA1, base_a, Ea, aidx,
        ca, haSp0[1], haSp1[1], haf,
        htSp0[0], htSp1[0], W10, W11, e2ts_b1, u,
        hrf, resT4, e2res_b, out_res, ridx, 64, 512);
    heads<<<512, blk, 0, stream>>>(haf, actT4, e2act_b, out_acts, aidx, -1,
                                   u, e2ts_w2, e2ts_b2, out_ts, tsv, 63);
}

// Round 3
// 14285.837 us; speedup vs baseline: 1.1587x; 1.0159x over previous
//
#include <hip/hip_runtime.h>
#include <math.h>

// Decoder: B=1024, Z=256, TDIM=512, CF=1024, A=64, R=128, T=64
// R10: A-operands loaded global->VGPR directly (same per-lane bytes as the old
//      GLDS path -> bit-identical MFMA inputs); only B (weights) staged in LDS.
//      LDS 48KB -> 16KB/block => 4 blocks/CU (launch_bounds(256,4)), step3's 1024
//      blocks fully co-resident (no tail round). Pipeline: STAGEB(next) ->
//      vmcnt(2) -> barrier -> LOADA(next) || COMPUTE(cur). Numerics unchanged.

__device__ __forceinline__ float sigf(float x) { return 1.0f / (1.0f + expf(-x)); }

typedef __attribute__((ext_vector_type(8))) _Float16 f16x8;
typedef __attribute__((ext_vector_type(4))) float f32x4;

__device__ __forceinline__ void split_f16(float x, unsigned short& hi, unsigned short& lo) {
    _Float16 h = (_Float16)x;                   // RNE f32->f16
    float r = (x - (float)h) * 2048.0f;         // exact
    _Float16 l = (_Float16)r;
    hi = __builtin_bit_cast(unsigned short, h);
    lo = __builtin_bit_cast(unsigned short, l);
}

#define GLDS(gp, lp) __builtin_amdgcn_global_load_lds( \
    (const __attribute__((address_space(1))) void*)(gp), \
    (__attribute__((address_space(3))) void*)(lp), 16, 0, 0)

// ---------------- step1: a-cell GEMM+LSTM | u GEMM | res head ----------------
// a: 128x64 tiles (64 N = 4 gates x 16 j), 4 waves (wm=wave, 32 rows each), ni=gate.
// u: 128x64 tiles over N=512.
// L<512: a (XCD-swizzled); 512..575: u; 576..831: res head for step t-1.
__global__ __launch_bounds__(256, 4) void step1(
    const unsigned short* __restrict__ Ah, const unsigned short* __restrict__ Al,
    const unsigned short* __restrict__ WA0, const unsigned short* __restrict__ WA1,
    const float* __restrict__ base_a, const float* __restrict__ Ea, const int* __restrict__ aidx,
    float* __restrict__ ca, unsigned short* __restrict__ oAh, unsigned short* __restrict__ oAl,
    float* __restrict__ haf,
    const unsigned short* __restrict__ Th, const unsigned short* __restrict__ Tl,
    const unsigned short* __restrict__ W10, const unsigned short* __restrict__ W11,
    const float* __restrict__ b1, float* __restrict__ u,
    const float* __restrict__ hrf, const float* __restrict__ resT4, const float* __restrict__ resb,
    float* __restrict__ out_res, int* __restrict__ ridx, int t, int Loff)
{
    int L = blockIdx.x + Loff;
    if (L >= 576) {
        // ---- res head for step t-1 ----
        if (t == 0) return;
        int lane = threadIdx.x & 63, w = threadIdx.x >> 6;
        int b = (L - 576) * 4 + w;
        float acc0 = resb[lane], acc1 = resb[lane + 64];
        const float4* arow = (const float4*)(hrf + (size_t)b * 1024);
#pragma unroll 4
        for (int k4 = 0; k4 < 256; k4++) {
            float4 a4 = arow[k4];
            float4 w40 = *(const float4*)(resT4 + ((size_t)k4 * 128 + lane) * 4);
            float4 w41 = *(const float4*)(resT4 + ((size_t)k4 * 128 + lane + 64) * 4);
            acc0 += a4.x * w40.x + a4.y * w40.y + a4.z * w40.z + a4.w * w40.w;
            acc1 += a4.x * w41.x + a4.y * w41.y + a4.z * w41.z + a4.w * w41.w;
        }
        float v = acc0; int idx = lane;
        if (acc1 > v) { v = acc1; idx = lane + 64; }
#pragma unroll
        for (int off = 32; off; off >>= 1) {
            float ov = __shfl_xor(v, off);
            int   oi = __shfl_xor(idx, off);
            if (ov > v || (ov == v && oi < idx)) { v = ov; idx = oi; }
        }
        float e0 = expf(acc0 - v), e1 = expf(acc1 - v);
        float s = e0 + e1;
#pragma unroll
        for (int off = 32; off; off >>= 1) s += __shfl_xor(s, off);
        float* dst = out_res + ((size_t)b * 64 + (t - 1)) * 128;
        dst[lane] = e0 / s; dst[lane + 64] = e1 / s;
        if (lane == 0) ridx[b] = idx;
        return;
    }

    // ---- GEMM part (a or u) ----
    // 16KB LDS: 2 bufs x 4096 ushorts {Bh[0,2048) Bl[2048,4096)}
    __shared__ unsigned short lds[8192];
    const unsigned short *pAh, *pAl, *pWh, *pWl;
    int x, jy; bool isA;
    if (L < 512) {
        isA = true;
        int xcd = L & 7, idx = L >> 3;
        jy = xcd * 8 + (idx >> 3);       // j-tile 0..63 (j0 = jy*16)
        x = idx & 7;
        pAh = Ah; pAl = Al; pWh = WA0; pWl = WA1;
    } else {
        isA = false;
        int t2 = L - 512;
        x = t2 & 7; jy = t2 >> 3;        // u: n0 = jy*64
        pAh = Th; pAl = Tl; pWh = W10; pWl = W11;
    }
    const int tid = threadIdx.x, wave = tid >> 6, lane = tid & 63;
    const int lrow = lane & 15, lq = lane >> 4;
    const int m0 = x * 128;

    f32x4 acch[2][4], accl[2][4];
#pragma unroll
    for (int i = 0; i < 2; i++)
#pragma unroll
        for (int j = 0; j < 4; j++) {
            acch[i][j] = (f32x4){0.f, 0.f, 0.f, 0.f};
            accl[i][j] = (f32x4){0.f, 0.f, 0.f, 0.f};
        }

    const int nrow = isA ? (wave * 1024 + jy * 16 + lrow) : (jy * 64 + wave * 16 + lrow);
    // per-lane A row bases (invariant): rows m0 + (wave*2+mi)*16 + lrow
    const size_t ar0 = (size_t)(m0 + (wave * 2 + 0) * 16 + lrow) * 1024 + lq * 8;
    const size_t ar1 = (size_t)(m0 + (wave * 2 + 1) * 16 + lrow) * 1024 + lq * 8;

    f16x8 ah[2][2], al[2][2];                       // [set][mi]

    // A-fragment loads straight to registers (same per-lane bytes as old GLDS path)
    auto LOADA = [&](int it, int s) {
        int k = it * 32;
        ah[s][0] = *(const f16x8*)(pAh + ar0 + k);
        al[s][0] = *(const f16x8*)(pAl + ar0 + k);
        ah[s][1] = *(const f16x8*)(pAh + ar1 + k);
        al[s][1] = *(const f16x8*)(pAl + ar1 + k);
    };
    // B stage into buffer p: 2 GLDS per wave (wave stages its own B region)
    auto STAGEB = [&](int it, int p) {
        int k = it * 32 + lq * 8;
        unsigned short* bp = &lds[p * 4096];
        GLDS(pWh + (size_t)nrow * 1024 + k, bp + wave * 512);
        GLDS(pWl + (size_t)nrow * 1024 + k, bp + 2048 + wave * 512);
    };
    // consume A-set s + B-buffer p: 8 ds_read_b128 + 24 MFMA (ni in halves for VGPR)
    auto COMPUTE = [&](int s, int p) {
        unsigned short* bp = &lds[p * 4096];
#pragma unroll
        for (int nh = 0; nh < 2; nh++) {
            f16x8 bh[2], bl[2];
#pragma unroll
            for (int q = 0; q < 2; q++) {
                int ni = nh * 2 + q;
                bh[q] = *(const f16x8*)(bp + ni * 512 + lane * 8);
                bl[q] = *(const f16x8*)(bp + 2048 + ni * 512 + lane * 8);
            }
#pragma unroll
            for (int mi = 0; mi < 2; mi++)
#pragma unroll
                for (int q = 0; q < 2; q++) {
                    int ni = nh * 2 + q;
                    acch[mi][ni] = __builtin_amdgcn_mfma_f32_16x16x32_f16(ah[s][mi], bh[q], acch[mi][ni], 0, 0, 0);
                    accl[mi][ni] = __builtin_amdgcn_mfma_f32_16x16x32_f16(al[s][mi], bh[q], accl[mi][ni], 0, 0, 0);
                    accl[mi][ni] = __builtin_amdgcn_mfma_f32_16x16x32_f16(ah[s][mi], bl[q], accl[mi][ni], 0, 0, 0);
                }
        }
    };

    LOADA(0, 0);
    STAGEB(0, 0);
    for (int it = 0; it < 30; it += 2) {
        // even phase: compute set0/buf0, prefetch it+1 -> set1/buf1
        STAGEB(it + 1, 1);
        asm volatile("s_waitcnt vmcnt(2)" ::: "memory");  // phase-it A+B complete
        __builtin_amdgcn_s_barrier();
        __builtin_amdgcn_sched_barrier(0);
        LOADA(it + 1, 1);
        COMPUTE(0, 0);
        __builtin_amdgcn_sched_barrier(0);
        __builtin_amdgcn_s_barrier();
        // odd phase: compute set1/buf1, prefetch it+2 -> set0/buf0
        STAGEB(it + 2, 0);
        asm volatile("s_waitcnt vmcnt(2)" ::: "memory");
        __builtin_amdgcn_s_barrier();
        __builtin_amdgcn_sched_barrier(0);
        LOADA(it + 2, 0);
        COMPUTE(1, 1);
        __builtin_amdgcn_sched_barrier(0);
        __builtin_amdgcn_s_barrier();
    }
    // phase 30: prefetch 31 -> set1/buf1
    STAGEB(31, 1);
    asm volatile("s_waitcnt vmcnt(2)" ::: "memory");
    __builtin_amdgcn_s_barrier();
    __builtin_amdgcn_sched_barrier(0);
    LOADA(31, 1);
    COMPUTE(0, 0);
    __builtin_amdgcn_sched_barrier(0);
    __builtin_amdgcn_s_barrier();
    // phase 31: no prefetch
    asm volatile("s_waitcnt vmcnt(0)" ::: "memory");
    __builtin_amdgcn_s_barrier();
    __builtin_amdgcn_sched_barrier(0);
    COMPUTE(1, 1);

    const float s_lo = 1.0f / 2048.0f;
    if (isA) {
        // fused LSTM-a epilogue: ni == gate, thread-local
        int j = jy * 16 + lrow;
#pragma unroll
        for (int mi = 0; mi < 2; mi++)
#pragma unroll
            for (int r = 0; r < 4; r++) {
                int row = m0 + wave * 32 + mi * 16 + lq * 4 + r;
                size_t rb = (size_t)row * 4096 + j;
                const float* e1 = Ea + (size_t)aidx[row] * 4096 + j;
                float gi = acch[mi][0][r] + accl[mi][0][r] * s_lo + base_a[rb]        + e1[0];
                float gf = acch[mi][1][r] + accl[mi][1][r] * s_lo + base_a[rb + 1024] + e1[1024];
                float gg = acch[mi][2][r] + accl[mi][2][r] * s_lo + base_a[rb + 2048] + e1[2048];
                float go = acch[mi][3][r] + accl[mi][3][r] * s_lo + base_a[rb + 3072] + e1[3072];
                size_t ci = (size_t)row * 1024 + j;
                float cn = sigf(gf) * ca[ci] + sigf(gi) * tanhf(gg);
                ca[ci] = cn;
                float hn = sigf(go) * tanhf(cn);
                haf[ci] = hn;
                split_f16(hn, oAh[ci], oAl[ci]);
            }
    } else {
        // u = relu(ht @ W1^T + b1)
#pragma unroll
        for (int mi = 0; mi < 2; mi++)
#pragma unroll
            for (int ni = 0; ni < 4; ni++) {
                int col = jy * 64 + ni * 16 + lrow;
                float bv = b1[col];
#pragma unroll
                for (int r = 0; r < 4; r++) {
                    int row = m0 + wave * 32 + mi * 16 + lq * 4 + r;
                    float v = acch[mi][ni][r] + accl[mi][ni][r] * s_lo + bv;
                    u[(size_t)row * 512 + col] = fmaxf(v, 0.0f);
                }
            }
    }
}

// ---------------- step3: r & t cell GEMM + fused LSTM epilogue ----------------
// 128x64 tiles (64 N = 4 gates x 16 j), wave==gate-stager, A in regs, B in 16KB LDS.
// 1024 blocks = 8 m-tiles x 128 (cell,j-tile) groups; XCD-swizzled; 4 blocks/CU ->
// whole grid co-resident.
__global__ __launch_bounds__(256, 4) void step3(
    const unsigned short* __restrict__ Rh, const unsigned short* __restrict__ Rl,
    const unsigned short* __restrict__ WR0, const unsigned short* __restrict__ WR1,
    const float* __restrict__ base_r, const float* __restrict__ Er_a, const float* __restrict__ Er_r,
    const int* __restrict__ aidx, const int* __restrict__ ridx, const float* __restrict__ tsv,
    float* __restrict__ cr, unsigned short* __restrict__ oRh, unsigned short* __restrict__ oRl,
    float* __restrict__ hrf,
    const unsigned short* __restrict__ Th, const unsigned short* __restrict__ Tl,
    const unsigned short* __restrict__ WT0, const unsigned short* __restrict__ WT1,
    const float* __restrict__ base_t, const float* __restrict__ Et_a, const float* __restrict__ wtts,
    float* __restrict__ ct, unsigned short* __restrict__ oTh, unsigned short* __restrict__ oTl)
{
    // 16KB LDS: 2 bufs x 4096 ushorts {Bh[0,2048) Bl[2048,4096)}
    __shared__ unsigned short lds[8192];
    int L = blockIdx.x;
    int xcd = L & 7, idx = L >> 3;
    int g = xcd * 16 + (idx >> 3);           // 128 (z, jy) groups
    int x = idx & 7;
    int z = g >> 6, jy = g & 63;
    const unsigned short* pAh = z ? Th : Rh;
    const unsigned short* pAl = z ? Tl : Rl;
    const unsigned short* pWh = z ? WT0 : WR0;
    const unsigned short* pWl = z ? WT1 : WR1;

    const int tid = threadIdx.x, wave = tid >> 6, lane = tid & 63;
    const int lrow = lane & 15, lq = lane >> 4;
    const int m0 = x * 128;

    f32x4 acch[2][4], accl[2][4];
#pragma unroll
    for (int i = 0; i < 2; i++)
#pragma unroll
        for (int j = 0; j < 4; j++) {
            acch[i][j] = (f32x4){0.f, 0.f, 0.f, 0.f};
            accl[i][j] = (f32x4){0.f, 0.f, 0.f, 0.f};
        }

    const int nrow = wave * 1024 + jy * 16 + lrow;   // wave == gate
    const size_t ar0 = (size_t)(m0 + (wave * 2 + 0) * 16 + lrow) * 1024 + lq * 8;
    const size_t ar1 = (size_t)(m0 + (wave * 2 + 1) * 16 + lrow) * 1024 + lq * 8;

    f16x8 ah[2][2], al[2][2];                       // [set][mi]

    auto LOADA = [&](int it, int s) {
        int k = it * 32;
        ah[s][0] = *(const f16x8*)(pAh + ar0 + k);
        al[s][0] = *(const f16x8*)(pAl + ar0 + k);
        ah[s][1] = *(const f16x8*)(pAh + ar1 + k);
        al[s][1] = *(const f16x8*)(pAl + ar1 + k);
    };
    auto STAGEB = [&](int it, int p) {
        int k = it * 32 + lq * 8;
        unsigned short* bp = &lds[p * 4096];
        GLDS(pWh + (size_t)nrow * 1024 + k, bp + wave * 512);
        GLDS(pWl + (size_t)nrow * 1024 + k, bp + 2048 + wave * 512);
    };
    auto COMPUTE = [&](int s, int p) {
        unsigned short* bp = &lds[p * 4096];
#pragma unroll
        for (int nh = 0; nh < 2; nh++) {
            f16x8 bh[2], bl[2];
#pragma unroll
            for (int q = 0; q < 2; q++) {
                int ni = nh * 2 + q;
                bh[q] = *(const f16x8*)(bp + ni * 512 + lane * 8);
                bl[q] = *(const f16x8*)(bp + 2048 + ni * 512 + lane * 8);
            }
#pragma unroll
            for (int mi = 0; mi < 2; mi++)
#pragma unroll
                for (int q = 0; q < 2; q++) {
                    int ni = nh * 2 + q;
                    acch[mi][ni] = __builtin_amdgcn_mfma_f32_16x16x32_f16(ah[s][mi], bh[q], acch[mi][ni], 0, 0, 0);
                    accl[mi][ni] = __builtin_amdgcn_mfma_f32_16x16x32_f16(al[s][mi], bh[q], accl[mi][ni], 0, 0, 0);
                    accl[mi][ni] = __builtin_amdgcn_mfma_f32_16x16x32_f16(ah[s][mi], bl[q], accl[mi][ni], 0, 0, 0);
                }
        }
    };

    LOADA(0, 0);
    STAGEB(0, 0);
    for (int it = 0; it < 30; it += 2) {
        STAGEB(it + 1, 1);
        asm volatile("s_waitcnt vmcnt(2)" ::: "memory");
        __builtin_amdgcn_s_barrier();
        __builtin_amdgcn_sched_barrier(0);
        LOADA(it + 1, 1);
        COMPUTE(0, 0);
        __builtin_amdgcn_sched_barrier(0);
        __builtin_amdgcn_s_barrier();
        STAGEB(it + 2, 0);
        asm volatile("s_waitcnt vmcnt(2)" ::: "memory");
        __builtin_amdgcn_s_barrier();
        __builtin_amdgcn_sched_barrier(0);
        LOADA(it + 2, 0);
        COMPUTE(1, 1);
        __builtin_amdgcn_sched_barrier(0);
        __builtin_amdgcn_s_barrier();
    }
    STAGEB(31, 1);
    asm volatile("s_waitcnt vmcnt(2)" ::: "memory");
    __builtin_amdgcn_s_barrier();
    __builtin_amdgcn_sched_barrier(0);
    LOADA(31, 1);
    COMPUTE(0, 0);
    __builtin_amdgcn_sched_barrier(0);
    __builtin_amdgcn_s_barrier();
    asm volatile("s_waitcnt vmcnt(0)" ::: "memory");
    __builtin_amdgcn_s_barrier();
    __builtin_amdgcn_sched_barrier(0);
    COMPUTE(1, 1);

    const float s_lo = 1.0f / 2048.0f;
    const int j = jy * 16 + lrow;
    if (z == 0) {
        // cell r
#pragma unroll
        for (int mi = 0; mi < 2; mi++)
#pragma unroll
            for (int r = 0; r < 4; r++) {
                int row = m0 + wave * 32 + mi * 16 + lq * 4 + r;
                size_t rb = (size_t)row * 4096 + j;
                const float* e1 = Er_a + (size_t)aidx[row] * 4096 + j;
                const float* e2 = Er_r + (size_t)ridx[row] * 4096 + j;
                float gi = acch[mi][0][r] + accl[mi][0][r] * s_lo + base_r[rb]        + e1[0]    + e2[0];
                float gf = acch[mi][1][r] + accl[mi][1][r] * s_lo + base_r[rb + 1024] + e1[1024] + e2[1024];
                float gg = acch[mi][2][r] + accl[mi][2][r] * s_lo + base_r[rb + 2048] + e1[2048] + e2[2048];
                float go = acch[mi][3][r] + accl[mi][3][r] * s_lo + base_r[rb + 3072] + e1[3072] + e2[3072];
                size_t ci = (size_t)row * 1024 + j;
                float cn = sigf(gf) * cr[ci] + sigf(gi) * tanhf(gg);
                cr[ci] = cn;
                float hn = sigf(go) * tanhf(cn);
                hrf[ci] = hn;
                split_f16(hn, oRh[ci], oRl[ci]);
            }
    } else {
        // cell t
#pragma unroll
        for (int mi = 0; mi < 2; mi++)
#pragma unroll
            for (int r = 0; r < 4; r++) {
                int row = m0 + wave * 32 + mi * 16 + lq * 4 + r;
                size_t rb = (size_t)row * 4096 + j;
                const float* e1 = Et_a + (size_t)aidx[row] * 4096 + j;
                float tv = tsv[row];
                float gi = acch[mi][0][r] + accl[mi][0][r] * s_lo + base_t[rb]        + e1[0];
                float gf = acch[mi][1][r] + accl[mi][1][r] * s_lo + base_t[rb + 1024] + e1[1024];
                float gg = acch[mi][2][r] + accl[mi][2][r] * s_lo + base_t[rb + 2048] + e1[2048];
                float go = acch[mi][3][r] + accl[mi][3][r] * s_lo + base_t[rb + 3072] + e1[3072];
                gi = fmaf(tv, wtts[j], gi);        gf = fmaf(tv, wtts[j + 1024], gf);
                gg = fmaf(tv, wtts[j + 2048], gg); go = fmaf(tv, wtts[j + 3072], go);
                size_t ci = (size_t)row * 1024 + j;
                float cn = sigf(gf) * ct[ci] + sigf(gi) * tanhf(gg);
                ct[ci] = cn;
                float hn = sigf(go) * tanhf(cn);
                split_f16(hn, oTh[ci], oTl[ci]);
            }
    }
}

// ---------------- heads: act softmax/argmax (blocks 0..255) + ts_final (256..511) ----------------
__global__ __launch_bounds__(256) void heads(
    const float* __restrict__ haf, const float* __restrict__ actT4, const float* __restrict__ actb,
    float* __restrict__ out_acts, int* __restrict__ aidx, int tact,
    const float* __restrict__ u, const float* __restrict__ w2, const float* __restrict__ b2,
    float* __restrict__ out_ts, float* __restrict__ tsv, int tts)
{
    int blk = blockIdx.x;
    int lane = threadIdx.x & 63, w = threadIdx.x >> 6;
    if (blk < 256) {
        if (tact < 0) return;
        int b = blk * 4 + w;
        float acc = actb[lane];
        const float4* arow = (const float4*)(haf + (size_t)b * 1024);
#pragma unroll 4
        for (int k4 = 0; k4 < 256; k4++) {
            float4 a4 = arow[k4];
            float4 w4 = *(const float4*)(actT4 + ((size_t)k4 * 64 + lane) * 4);
            acc += a4.x * w4.x + a4.y * w4.y + a4.z * w4.z + a4.w * w4.w;
        }
        float v = acc; int idx = lane;
#pragma unroll
        for (int off = 32; off; off >>= 1) {
            float ov = __shfl_xor(v, off);
            int   oi = __shfl_xor(idx, off);
            if (ov > v || (ov == v && oi < idx)) { v = ov; idx = oi; }
        }
        float e = expf(acc - v);
        float s = e;
#pragma unroll
        for (int off = 32; off; off >>= 1) s += __shfl_xor(s, off);
        out_acts[((size_t)b * 64 + tact) * 64 + lane] = e / s;
        if (lane == 0) aidx[b] = idx;
    } else {
        if (tts < 0) return;
        int b = (blk - 256) * 4 + w;
        const float* ur = u + (size_t)b * 512;
        float s = 0.0f;
#pragma unroll
        for (int q = 0; q < 8; q++) s = fmaf(ur[lane + q * 64], w2[lane + q * 64], s);
#pragma unroll
        for (int off = 32; off; off >>= 1) s += __shfl_xor(s, off);
        if (lane == 0) {
            float r = s + b2[0];
            out_ts[b * 64 + tts] = r;
            tsv[b] = r;
        }
    }
}

// ---------------- fp32 GEMM (setup only) ----------------
__global__ __launch_bounds__(256) void gemm_f32(
    const float* __restrict__ A0, const float* __restrict__ W0, float* __restrict__ C0,
    const float* __restrict__ A1, const float* __restrict__ W1, float* __restrict__ C1,
    int lda, int ldw, int ldc, int K, const float* __restrict__ bias, int relu)
{
    const float* Ap = blockIdx.z ? A1 : A0;
    const float* Wp = blockIdx.z ? W1 : W0;
    float*       Cp = blockIdx.z ? C1 : C0;
    __shared__ float As[16][128];
    __shared__ float Bs[16][64];
    const int tid = threadIdx.x;
    const int m0 = blockIdx.x * 128, n0 = blockIdx.y * 64;
    const int tx = tid & 7, ty = tid >> 3;
    const bool wal = (ldw & 3) == 0;
    float acc[4][8];
#pragma unroll
    for (int i = 0; i < 4; i++)
#pragma unroll
        for (int j = 0; j < 8; j++) acc[i][j] = 0.0f;

    for (int k0 = 0; k0 < K; k0 += 16) {
        __syncthreads();
#pragma unroll
        for (int q = 0; q < 2; q++) {
            int t2 = tid + q * 256;
            int kq = t2 & 3, m = t2 >> 2;
            float4 v = *(const float4*)(Ap + (size_t)(m0 + m) * lda + k0 + kq * 4);
            As[kq * 4 + 0][m] = v.x; As[kq * 4 + 1][m] = v.y;
            As[kq * 4 + 2][m] = v.z; As[kq * 4 + 3][m] = v.w;
        }
        {
            int kq = tid & 3, n = tid >> 2;
            const float* src = Wp + (size_t)(n0 + n) * ldw + k0 + kq * 4;
            float4 v;
            if (wal) v = *(const float4*)src;
            else { v.x = src[0]; v.y = src[1]; v.z = src[2]; v.w = src[3]; }
            Bs[kq * 4 + 0][n] = v.x; Bs[kq * 4 + 1][n] = v.y;
            Bs[kq * 4 + 2][n] = v.z; Bs[kq * 4 + 3][n] = v.w;
        }
        __syncthreads();
#pragma unroll
        for (int k = 0; k < 16; k++) {
            float a4[4], b8[8];
            *(float4*)a4 = *(const float4*)&As[k][ty * 4];
            *(float4*)(b8) = *(const float4*)&Bs[k][tx * 8];
            *(float4*)(b8 + 4) = *(const float4*)&Bs[k][tx * 8 + 4];
#pragma unroll
            for (int i = 0; i < 4; i++)
#pragma unroll
                for (int j = 0; j < 8; j++) acc[i][j] = fmaf(a4[i], b8[j], acc[i][j]);
        }
    }
#pragma unroll
    for (int i = 0; i < 4; i++) {
        int m = m0 + ty * 4 + i;
        float vb[8];
#pragma unroll
        for (int j = 0; j < 8; j++) {
            float v = acc[i][j];
            if (bias) v += bias[n0 + tx * 8 + j];
            if (relu) v = fmaxf(v, 0.0f);
            vb[j] = v;
        }
        float* dst = Cp + (size_t)m * ldc + n0 + tx * 8;
        *(float4*)dst = make_float4(vb[0], vb[1], vb[2], vb[3]);
        *(float4*)(dst + 4) = make_float4(vb[4], vb[5], vb[6], vb[7]);
    }
}

// ------------- setup kernels -------------
__global__ void extract_cols(const float* __restrict__ Wih, int ldw, int col0, int ncols,
                             float* __restrict__ E)
{
    int i = blockIdx.x * 256 + threadIdx.x;
    if (i >= ncols * 4096) return;
    int c = i % ncols, j = i / ncols;
    E[(size_t)c * 4096 + j] = Wih[(size_t)j * ldw + col0 + c];
}

__global__ void split_mat_h(const float* __restrict__ X,
                            unsigned short* __restrict__ hi, unsigned short* __restrict__ lo, int n)
{
    int i = blockIdx.x * 256 + threadIdx.x;
    if (i >= n) return;
    split_f16(X[i], hi[i], lo[i]);
}

// pack-transpose: out[((k>>2)*C + c)*4 + (k&3)] = W[c*K + k]
__global__ void transpose_pack(const float* __restrict__ W, int K, int C, float* __restrict__ out)
{
    int i = blockIdx.x * 256 + threadIdx.x;
    if (i >= C * K) return;
    int c = i / K, k = i - c * K;
    out[(((size_t)(k >> 2) * C + c) << 2) + (k & 3)] = W[i];
}

__global__ void init_state(float* __restrict__ cc, unsigned int* __restrict__ hilo,
                           float* __restrict__ tsv, int* __restrict__ aidx, int* __restrict__ ridx)
{
    int i = blockIdx.x * 256 + threadIdx.x;
    if (i < 3 * 1024 * 1024) cc[i] = 0.0f;
    if (i < 6 * 1024 * 1024) hilo[i] = 0u;          // 12M ushort of split state
    if (i < 1024) { tsv[i] = 0.0f; aidx[i] = 63; ridx[i] = 127; }
}

extern "C" void kernel_launch(void* const* d_in, const int* in_sizes, int n_in,
                              void* d_out, int out_size, void* d_ws, size_t ws_size,
                              hipStream_t stream)
{
    const float* z       = (const float*)d_in[0];
    const float* z2t_w   = (const float*)d_in[1];
    const float* z2t_b   = (const float*)d_in[2];
    const float* Wih_a   = (const float*)d_in[3];
    const float* Whh_a   = (const float*)d_in[4];
    const float* b_a     = (const float*)d_in[5];
    const float* Wih_r   = (const float*)d_in[6];
    const float* Whh_r   = (const float*)d_in[7];
    const float* b_r     = (const float*)d_in[8];
    const float* Wih_t   = (const float*)d_in[9];
    const float* Whh_t   = (const float*)d_in[10];
    const float* b_t     = (const float*)d_in[11];
    const float* e2act_w = (const float*)d_in[12];
    const float* e2act_b = (const float*)d_in[13];
    const float* e2res_w = (const float*)d_in[14];
    const float* e2res_b = (const float*)d_in[15];
    const float* e2ts_w1 = (const float*)d_in[16];
    const float* e2ts_b1 = (const float*)d_in[17];
    const float* e2ts_w2 = (const float*)d_in[18];
    const float* e2ts_b2 = (const float*)d_in[19];

    float* out_acts = (float*)d_out;                     // [1024][64][64]
    float* out_ts   = out_acts + (size_t)1024 * 64 * 64; // [1024][64]
    float* out_res  = out_ts + 1024 * 64;                // [1024][64][128]

    float* ws = (float*)d_ws;
    size_t off = 0;
    auto alloc = [&](size_t n) { float* p = ws + off; off += n; return p; };
    float* t_rec  = alloc((size_t)1024 * 512);
    float* base_a = alloc((size_t)1024 * 4096);
    float* base_r = alloc((size_t)1024 * 4096);
    float* base_t = alloc((size_t)1024 * 4096);
    float* Ea     = alloc((size_t)64 * 4096);
    float* Er_a   = alloc((size_t)64 * 4096);
    float* Er_r   = alloc((size_t)128 * 4096);
    float* Et_a   = alloc((size_t)64 * 4096);
    float* wtts   = alloc(4096);
    float* cc     = alloc((size_t)3 * 1024 * 1024);      // ca, cr, ct
    float* ca = cc, * cr = cc + 1048576, * ct = cc + 2097152;
    float* haf    = alloc((size_t)1024 * 1024);
    float* hrf    = alloc((size_t)1024 * 1024);
    float* u      = alloc((size_t)1024 * 512);
    float* tsv    = alloc(1024);
    int*   aidx   = (int*)alloc(1024);
    int*   ridx   = (int*)alloc(1024);
    float* actT4  = alloc((size_t)64 * 1024);
    float* resT4  = alloc((size_t)128 * 1024);
    // ping-pong split state: 12 x 1M ushort = 6M floats
    unsigned short* hilo = (unsigned short*)alloc((size_t)6 * 1024 * 1024);
    const size_t U = 1048576;
    unsigned short* haSp0[2] = {hilo,         hilo + U};
    unsigned short* haSp1[2] = {hilo + 2 * U, hilo + 3 * U};
    unsigned short* hrSp0[2] = {hilo + 4 * U, hilo + 5 * U};
    unsigned short* hrSp1[2] = {hilo + 6 * U, hilo + 7 * U};
    unsigned short* htSp0[2] = {hilo + 8 * U, hilo + 9 * U};
    unsigned short* htSp1[2] = {hilo + 10 * U, hilo + 11 * U};
    // split weights
    unsigned short* WA0 = (unsigned short*)alloc((size_t)2 * 1024 * 1024);
    unsigned short* WA1 = (unsigned short*)alloc((size_t)2 * 1024 * 1024);
    unsigned short* WR0 = (unsigned short*)alloc((size_t)2 * 1024 * 1024);
    unsigned short* WR1 = (unsigned short*)alloc((size_t)2 * 1024 * 1024);
    unsigned short* WT0 = (unsigned short*)alloc((size_t)2 * 1024 * 1024);
    unsigned short* WT1 = (unsigned short*)alloc((size_t)2 * 1024 * 1024);
    unsigned short* W10 = (unsigned short*)alloc((size_t)256 * 1024);
    unsigned short* W11 = (unsigned short*)alloc((size_t)256 * 1024);

    dim3 blk(256);
    init_state<<<(6 * 1024 * 1024 + 255) / 256, blk, 0, stream>>>(cc, (unsigned int*)hilo, tsv, aidx, ridx);

    // t_rec = relu(z @ z2t_w.T + z2t_b)
    gemm_f32<<<dim3(8, 8, 1), blk, 0, stream>>>(z, z2t_w, t_rec, z, z2t_w, t_rec,
                                                256, 256, 512, 256, z2t_b, 1);
    // base_* = t_rec @ Wih_*[:, :512].T + b_*
    gemm_f32<<<dim3(8, 64, 1), blk, 0, stream>>>(t_rec, Wih_a, base_a, t_rec, Wih_a, base_a,
                                                 512, 576, 4096, 512, b_a, 0);
    gemm_f32<<<dim3(8, 64, 1), blk, 0, stream>>>(t_rec, Wih_r, base_r, t_rec, Wih_r, base_r,
                                                 512, 704, 4096, 512, b_r, 0);
    gemm_f32<<<dim3(8, 64, 1), blk, 0, stream>>>(t_rec, Wih_t, base_t, t_rec, Wih_t, base_t,
                                                 512, 577, 4096, 512, b_t, 0);
    // one-hot column tables
    extract_cols<<<(64 * 4096 + 255) / 256, blk, 0, stream>>>(Wih_a, 576, 512, 64, Ea);
    extract_cols<<<(64 * 4096 + 255) / 256, blk, 0, stream>>>(Wih_r, 704, 512, 64, Er_a);
    extract_cols<<<(128 * 4096 + 255) / 256, blk, 0, stream>>>(Wih_r, 704, 576, 128, Er_r);
    extract_cols<<<(64 * 4096 + 255) / 256, blk, 0, stream>>>(Wih_t, 577, 512, 64, Et_a);
    extract_cols<<<(4096 + 255) / 256, blk, 0, stream>>>(Wih_t, 577, 576, 1, wtts);
    // head weight transposes
    transpose_pack<<<(64 * 1024 + 255) / 256, blk, 0, stream>>>(e2act_w, 1024, 64, actT4);
    transpose_pack<<<(128 * 1024 + 255) / 256, blk, 0, stream>>>(e2res_w, 1024, 128, resT4);
    // weight splits (fp16 hi/lo, lo scaled by 2^11)
    split_mat_h<<<(4194304 + 255) / 256, blk, 0, stream>>>(Whh_a, WA0, WA1, 4194304);
    split_mat_h<<<(4194304 + 255) / 256, blk, 0, stream>>>(Whh_r, WR0, WR1, 4194304);
    split_mat_h<<<(4194304 + 255) / 256, blk, 0, stream>>>(Whh_t, WT0, WT1, 4194304);
    split_mat_h<<<(524288 + 255) / 256, blk, 0, stream>>>(e2ts_w1, W10, W11, 524288);

    for (int t = 0; t < 64; t++) {
        int rd = t & 1, wr = rd ^ 1;
        step1<<<832, blk, 0, stream>>>(
            haSp0[rd], haSp1[rd], WA0, WA1, base_a, Ea, aidx,
            ca, haSp0[wr], haSp1[wr], haf,
            htSp0[rd], htSp1[rd], W10, W11, e2ts_b1, u,
            hrf, resT4, e2res_b, out_res, ridx, t, 0);
        heads<<<512, blk, 0, stream>>>(haf, actT4, e2act_b, out_acts, aidx, t,
                                       u, e2ts_w2, e2ts_b2, out_ts, tsv, t - 1);
        step3<<<1024, blk, 0, stream>>>(
            hrSp0[rd], hrSp1[rd], WR0, WR1, base_r, Er_a, Er_r, aidx, ridx, tsv,
            cr, hrSp0[wr], hrSp1[wr], hrf,
            htSp0[rd], htSp1[rd], WT0, WT1, base_t, Et_a, wtts,
            ct, htSp0[wr], htSp1[wr]);
    }
    // tail: u(63) from ht(63) (buffers at index 64&1=0), res(63), ts(63)
    step1<<<320, blk, 0, stream>>>(
        haSp0[0], haSp1[0], WA0, WA1, base_a, Ea, aidx,
        ca, haSp0[1], haSp1[1], haf,
        htSp0[0], htSp1[0], W10, W11, e2ts_b1, u,
        hrf, resT4, e2res_b, out_res, ridx, 64, 512);
    heads<<<512, blk, 0, stream>>>(haf, actT4, e2act_b, out_acts, aidx, -1,
                                   u, e2ts_w2, e2ts_b2, out_ts, tsv, 63);
}